// Round 7
// baseline (211.751 us; speedup 1.0000x reference)
//
#include <hip/hip_runtime.h>
#include <math.h>

// S6 (Mamba-style) block, B=2 S=2048 Dm=768 Di=1536 Ds=16 K=4.
// Round 7: (a) GEMMs get explicit double-buffer prefetch (issue next-tile
//          global_load_lds before current-tile MFMA; one vmcnt(0)+barrier
//          per K-step) — R6 showed 1.2 blocks/CU, so cross-block overlap
//          can't hide the staging drain; intra-block pipelining must.
//          (b) GEMM3 -> 128x64 tile. (c) rms+cvt fused. (d) xc stored bf16
//          (written 1x read 3x), xssm vectorized short4/float4.

#define DM   768
#define DI   1536
#define DS2  16
#define SEQN 2048
#define BSZ  2
#define NROWS (BSZ*SEQN)   // 4096
#define CHUNK 32
#define NCHUNK (SEQN/CHUNK) // 64

#define AS1 __attribute__((address_space(1)))
#define AS3 __attribute__((address_space(3)))

typedef short short8 __attribute__((ext_vector_type(8)));
typedef short short4v __attribute__((ext_vector_type(4)));
typedef float f32x4 __attribute__((ext_vector_type(4)));

__device__ __forceinline__ unsigned short f2bf(float f) {
  unsigned u = __builtin_bit_cast(unsigned, f);
  unsigned r = (u + 0x7FFFu + ((u >> 16) & 1u)) >> 16;   // RTNE
  return (unsigned short)r;
}
__device__ __forceinline__ float bf2f(short s) {
  unsigned u = ((unsigned)(unsigned short)s) << 16;
  return __builtin_bit_cast(float, u);
}

// ---------------- K1: fused rmsnorm + bf16 convert -------------------------
// one wave per row; 12 floats per lane (3 float4s)
__global__ __launch_bounds__(256) void rms_xn_k(const float* __restrict__ x,
                                                const float* __restrict__ nw,
                                                short* __restrict__ xn) {
  int wv = threadIdx.x >> 6, lane = threadIdx.x & 63;
  int row = blockIdx.x * 4 + wv;
  const float* xr = x + (size_t)row * DM;
  float4 v[3];
  float s = 0.f;
#pragma unroll
  for (int i = 0; i < 3; ++i) {
    v[i] = *reinterpret_cast<const float4*>(&xr[(i * 64 + lane) * 4]);
    s = fmaf(v[i].x, v[i].x, s); s = fmaf(v[i].y, v[i].y, s);
    s = fmaf(v[i].z, v[i].z, s); s = fmaf(v[i].w, v[i].w, s);
  }
#pragma unroll
  for (int off = 32; off >= 1; off >>= 1) s += __shfl_xor(s, off, 64);
  float rs = rsqrtf(s * (1.f / DM) + 1e-6f);
#pragma unroll
  for (int i = 0; i < 3; ++i) {
    const float4 w = *reinterpret_cast<const float4*>(&nw[(i * 64 + lane) * 4]);
    short4v o;
    o.x = (short)f2bf(v[i].x * rs * w.x); o.y = (short)f2bf(v[i].y * rs * w.y);
    o.z = (short)f2bf(v[i].z * rs * w.z); o.w = (short)f2bf(v[i].w * rs * w.w);
    *reinterpret_cast<short4v*>(&xn[(size_t)row * DM + (i * 64 + lane) * 4]) = o;
  }
}

// ---------------- K1c: dst[c][r] = bf16(src[r][c]) (tiled transpose) -------
__global__ __launch_bounds__(256) void cvt_transpose_k(const float* __restrict__ src,
                                                       int rows, int cols,
                                                       short* __restrict__ dst) {
  __shared__ float t[32][33];
  int r0 = blockIdx.y * 32, c0 = blockIdx.x * 32;
  int tid = threadIdx.x;
  int lr = tid >> 3, lc4 = (tid & 7) * 4;
  float4 v = *reinterpret_cast<const float4*>(&src[(size_t)(r0 + lr) * cols + c0 + lc4]);
  t[lr][lc4 + 0] = v.x; t[lr][lc4 + 1] = v.y; t[lr][lc4 + 2] = v.z; t[lr][lc4 + 3] = v.w;
  __syncthreads();
  int orow = tid >> 3, oc4 = (tid & 7) * 4;
  short4v o;
  o.x = (short)f2bf(t[oc4 + 0][orow]); o.y = (short)f2bf(t[oc4 + 1][orow]);
  o.z = (short)f2bf(t[oc4 + 2][orow]); o.w = (short)f2bf(t[oc4 + 3][orow]);
  *reinterpret_cast<short4v*>(&dst[(size_t)(c0 + orow) * rows + r0 + oc4]) = o;
}

// ---------------- K1d: wxT[j][k] = wx[k][j]  (33 x 1536, f32) --------------
__global__ __launch_bounds__(256) void wxT_k(const float* __restrict__ wx,
                                             float* __restrict__ wxT) {
  int idx = blockIdx.x * 256 + threadIdx.x;
  if (idx >= DI * 33) return;
  int k = idx / 33, j = idx % 33;
  wxT[(size_t)j * DI + k] = wx[idx];
}

// ---------------- bf16 MFMA GEMM, double-buffered prefetch -----------------
// C = [res +] A @ B^T.  A:[M][K] bf16, Bt:[N][K] bf16. BK=64, 4 waves (2x2).
// Per K-step: issue next-tile global_load_lds into buf^1, MFMA from buf,
// single vmcnt(0)+barrier (via __syncthreads) at step end.
template<int BM, int BN, bool OUTBF>
__global__ __launch_bounds__(256) void gemm_bf16(
    const short* __restrict__ A, int lda,
    const short* __restrict__ Bt, int ldb,
    void* __restrict__ Cv, int ldc, int K,
    const float* __restrict__ res, int ldr)
{
  constexpr int MI = BM / 32, NJ = BN / 32;
  __shared__ __align__(16) short As[2 * BM * 64];
  __shared__ __align__(16) short Bs[2 * BN * 64];
  const int tid = threadIdx.x;
  const int w = tid >> 6, lane = tid & 63;
  const int wr = w >> 1, wc = w & 1;
  const int m0 = blockIdx.y * BM, n0 = blockIdx.x * BN;
  const int l15 = lane & 15, l4 = lane >> 4;
  const int srow = lane >> 3;          // row within 8-row chunk
  const int skb = (lane & 7) * 8;      // k element offset (16B per lane)

  f32x4 acc[MI][NJ];
#pragma unroll
  for (int i = 0; i < MI; ++i)
#pragma unroll
    for (int j = 0; j < NJ; ++j) acc[i][j] = (f32x4){0.f, 0.f, 0.f, 0.f};

  auto STAGE = [&](int buf, int k0) {
#pragma unroll
    for (int q = 0; q < MI; ++q) {     // A: BM/8 chunks of 8 rows
      int c = w * MI + q;
      __builtin_amdgcn_global_load_lds(
          (const AS1 unsigned int*)(A + (size_t)(m0 + 8 * c + srow) * lda + k0 + skb),
          (AS3 unsigned int*)((char*)As + buf * (BM * 128) + c * 1024), 16, 0, 0);
    }
#pragma unroll
    for (int q = 0; q < NJ; ++q) {     // B: BN/8 chunks
      int c = w * NJ + q;
      __builtin_amdgcn_global_load_lds(
          (const AS1 unsigned int*)(Bt + (size_t)(n0 + 8 * c + srow) * ldb + k0 + skb),
          (AS3 unsigned int*)((char*)Bs + buf * (BN * 128) + c * 1024), 16, 0, 0);
    }
  };

  STAGE(0, 0);
  __syncthreads();                      // vmcnt(0) drain + barrier
  int cur = 0;
  const int NT = K / 64;
  for (int t = 0; t < NT; ++t) {
    if (t + 1 < NT) STAGE(cur ^ 1, (t + 1) * 64);   // prefetch overlaps MFMA
    const short* Ab = As + cur * BM * 64;
    const short* Bb = Bs + cur * BN * 64;
#pragma unroll
    for (int kk = 0; kk < 2; ++kk) {
      short8 a[MI], b[NJ];
#pragma unroll
      for (int i = 0; i < MI; ++i)
        a[i] = *reinterpret_cast<const short8*>(
            &Ab[(wr * (BM / 2) + i * 16 + l15) * 64 + kk * 32 + l4 * 8]);
#pragma unroll
      for (int j = 0; j < NJ; ++j)
        b[j] = *reinterpret_cast<const short8*>(
            &Bb[(wc * (BN / 2) + j * 16 + l15) * 64 + kk * 32 + l4 * 8]);
#pragma unroll
      for (int i = 0; i < MI; ++i)
#pragma unroll
        for (int j = 0; j < NJ; ++j)
          acc[i][j] = __builtin_amdgcn_mfma_f32_16x16x32_bf16(a[i], b[j], acc[i][j], 0, 0, 0);
    }
    __syncthreads();                    // waits prefetch + guards buf reuse
    cur ^= 1;
  }

#pragma unroll
  for (int i = 0; i < MI; ++i) {
#pragma unroll
    for (int j = 0; j < NJ; ++j) {
      int col = n0 + wc * (BN / 2) + j * 16 + l15;
#pragma unroll
      for (int r = 0; r < 4; ++r) {
        int row = m0 + wr * (BM / 2) + i * 16 + l4 * 4 + r;
        float v = acc[i][j][r];
        if constexpr (OUTBF) {
          ((short*)Cv)[(size_t)row * ldc + col] = (short)f2bf(v);
        } else {
          if (res) v += res[(size_t)row * ldr + col];
          ((float*)Cv)[(size_t)row * ldc + col] = v;
        }
      }
    }
  }
}

// ---------------- K3: depthwise causal conv(K=4) + bias + SiLU -------------
// reads bf16 xz[:, 0:1536], writes bf16 xc
__global__ __launch_bounds__(256) void conv_silu_k(const short* __restrict__ xz,
                                                   const float* __restrict__ cw,
                                                   const float* __restrict__ cb,
                                                   short* __restrict__ xc) {
  int idx = blockIdx.x * 256 + threadIdx.x;
  int d = idx % DI;
  int bt = idx / DI;
  int t = bt & (SEQN - 1);
  float acc = cb[d];
  const float4 w4 = *reinterpret_cast<const float4*>(&cw[d * 4]);
  const float wv[4] = {w4.x, w4.y, w4.z, w4.w};
  const short* base = xz + (size_t)bt * 3072 + d;
#pragma unroll
  for (int k = 0; k < 4; ++k) {
    int tt = t + k - 3;
    if (tt >= 0) acc = fmaf(bf2f(base[(ptrdiff_t)(k - 3) * 3072]), wv[k], acc);
  }
  xc[idx] = (short)f2bf(acc / (1.f + __expf(-acc)));
}

// ---------------- K4: x_ssm = xc @ wxT^T, 2 rows/wave, vectorized ----------
__global__ __launch_bounds__(256) void xssm_k(const short* __restrict__ xc,
                                              const float* __restrict__ wxT,
                                              float* __restrict__ Bm,
                                              float* __restrict__ Cm,
                                              float* __restrict__ dtr) {
  int wv = threadIdx.x >> 6, lane = threadIdx.x & 63;
  int row0 = (blockIdx.x * 4 + wv) * 2;
  const short* xr0 = xc + (size_t)row0 * DI;
  const short* xr1 = xr0 + DI;
  float a0[33], a1[33];
#pragma unroll
  for (int j = 0; j < 33; ++j) { a0[j] = 0.f; a1[j] = 0.f; }
  for (int k0 = lane * 4; k0 < DI; k0 += 256) {    // 6 iters, 4 elems each
    short4v s0 = *reinterpret_cast<const short4v*>(&xr0[k0]);
    short4v s1 = *reinterpret_cast<const short4v*>(&xr1[k0]);
    float x00 = bf2f(s0.x), x01 = bf2f(s0.y), x02 = bf2f(s0.z), x03 = bf2f(s0.w);
    float x10 = bf2f(s1.x), x11 = bf2f(s1.y), x12 = bf2f(s1.z), x13 = bf2f(s1.w);
#pragma unroll
    for (int j = 0; j < 33; ++j) {
      const float4 wq = *reinterpret_cast<const float4*>(&wxT[(size_t)j * DI + k0]);
      a0[j] = fmaf(x00, wq.x, fmaf(x01, wq.y, fmaf(x02, wq.z, fmaf(x03, wq.w, a0[j]))));
      a1[j] = fmaf(x10, wq.x, fmaf(x11, wq.y, fmaf(x12, wq.z, fmaf(x13, wq.w, a1[j]))));
    }
  }
#pragma unroll
  for (int j = 0; j < 33; ++j) {
#pragma unroll
    for (int off = 32; off >= 1; off >>= 1) {
      a0[j] += __shfl_xor(a0[j], off, 64);
      a1[j] += __shfl_xor(a1[j], off, 64);
    }
  }
  if (lane == 0) {
#pragma unroll
    for (int j = 0; j < 16; ++j) Bm[(size_t)row0 * 16 + j] = a0[j];
#pragma unroll
    for (int j = 0; j < 16; ++j) Cm[(size_t)row0 * 16 + j] = a0[16 + j];
    dtr[row0] = a0[32];
#pragma unroll
    for (int j = 0; j < 16; ++j) Bm[(size_t)(row0 + 1) * 16 + j] = a1[j];
#pragma unroll
    for (int j = 0; j < 16; ++j) Cm[(size_t)(row0 + 1) * 16 + j] = a1[16 + j];
    dtr[row0 + 1] = a1[32];
  }
}

// ---------------- K5a: per-chunk local scan, thread = one d-channel --------
__global__ __launch_bounds__(256) void scan_part1(
    const short* __restrict__ xc,
    const float* __restrict__ Bm, const float* __restrict__ dtr,
    const float* __restrict__ w_dt, const float* __restrict__ b_dt,
    const float* __restrict__ A_log,
    float* __restrict__ hL, float* __restrict__ Tsum)
{
  const int blk = blockIdx.x;
  const int c  = blk % NCHUNK;
  const int db = (blk / NCHUNK) % (DI / 256);
  const int b  = blk / (NCHUNK * (DI / 256));
  const int tid = threadIdx.x;
  const int d = db * 256 + tid;
  const size_t cb = (size_t)b * SEQN + c * CHUNK;

  __shared__ float sB[CHUNK][16];
  __shared__ float sdt[CHUNK];
  if (tid < CHUNK * 4)
    reinterpret_cast<float4*>(&sB[0][0])[tid] =
        reinterpret_cast<const float4*>(&Bm[cb * 16])[tid];
  if (tid < CHUNK / 4)
    reinterpret_cast<float4*>(sdt)[tid] =
        reinterpret_cast<const float4*>(&dtr[cb])[tid];
  __syncthreads();

  const float wdt = w_dt[d], bdt = b_dt[d];
  float a[DS2], h[DS2];
#pragma unroll
  for (int q = 0; q < 4; ++q) {
    float4 al = *reinterpret_cast<const float4*>(&A_log[(size_t)d * DS2 + q * 4]);
    a[q * 4 + 0] = -__expf(al.x); a[q * 4 + 1] = -__expf(al.y);
    a[q * 4 + 2] = -__expf(al.z); a[q * 4 + 3] = -__expf(al.w);
  }
#pragma unroll
  for (int n = 0; n < DS2; ++n) h[n] = 0.f;
  float T = 0.f;

#pragma unroll 2
  for (int tt = 0; tt < CHUNK; ++tt) {
    float v = fmaf(sdt[tt], wdt, bdt);
    float dtv = (v > 15.f) ? v : __logf(1.f + __expf(v));
    T += dtv;
    float xv = bf2f(xc[(cb + tt) * DI + d]);
    float s = dtv * xv;
    float bb[DS2];
#pragma unroll
    for (int q = 0; q < 4; ++q)
      *reinterpret_cast<float4*>(&bb[q * 4]) =
          *reinterpret_cast<const float4*>(&sB[tt][q * 4]);
#pragma unroll
    for (int n = 0; n < DS2; ++n)
      h[n] = fmaf(__expf(a[n] * dtv), h[n], s * bb[n]);
  }

  const size_t base = (size_t)(b * NCHUNK + c) * DI + d;
#pragma unroll
  for (int q = 0; q < 4; ++q)
    *reinterpret_cast<float4*>(&hL[base * 16 + q * 4]) =
        *reinterpret_cast<const float4*>(&h[q * 4]);
  Tsum[base] = T;
}

// ---------------- K5b: sequential chunk-combine, in place ------------------
__global__ __launch_bounds__(256) void scan_combine_k(
    float* __restrict__ hLH, const float* __restrict__ Tsum,
    const float* __restrict__ A_log)
{
  int g = blockIdx.x * 256 + threadIdx.x;
  int n = g & 15;
  int d = (g >> 4) % DI;
  int b = g / (DI * DS2);
  const float a = -__expf(A_log[(size_t)d * DS2 + n]);
  float h = 0.f;
  for (int c = 0; c < NCHUNK; ++c) {
    size_t base = (size_t)(b * NCHUNK + c) * DI + d;
    float hl = hLH[base * 16 + n];
    float T = Tsum[base];
    float hprev = h;
    h = fmaf(__expf(a * T), h, hl);
    hLH[base * 16 + n] = hprev;
  }
}

// ---------------- K5c: replay chunk with H_init + fused epilogue -----------
__global__ __launch_bounds__(256) void scan_part3(
    const short* __restrict__ xc,
    const short* __restrict__ xz,    // read z (bf16) at cols 1536..
    short* __restrict__ ybf,
    const float* __restrict__ Bm, const float* __restrict__ Cm,
    const float* __restrict__ dtr,
    const float* __restrict__ w_dt, const float* __restrict__ b_dt,
    const float* __restrict__ A_log, const float* __restrict__ Dp,
    const float* __restrict__ Hinit)
{
  const int blk = blockIdx.x;
  const int c  = blk % NCHUNK;
  const int db = (blk / NCHUNK) % (DI / 256);
  const int b  = blk / (NCHUNK * (DI / 256));
  const int tid = threadIdx.x;
  const int d = db * 256 + tid;
  const size_t cb = (size_t)b * SEQN + c * CHUNK;

  __shared__ float sB[CHUNK][16], sC[CHUNK][16];
  __shared__ float sdt[CHUNK];
  if (tid < CHUNK * 4)
    reinterpret_cast<float4*>(&sB[0][0])[tid] =
        reinterpret_cast<const float4*>(&Bm[cb * 16])[tid];
  else if (tid < CHUNK * 8)
    reinterpret_cast<float4*>(&sC[0][0])[tid - CHUNK * 4] =
        reinterpret_cast<const float4*>(&Cm[cb * 16])[tid - CHUNK * 4];
  if (tid < CHUNK / 4)
    reinterpret_cast<float4*>(sdt)[tid] =
        reinterpret_cast<const float4*>(&dtr[cb])[tid];

  const float wdt = w_dt[d], bdt = b_dt[d];
  const float Dd = Dp[d];
  float a[DS2], h[DS2];
#pragma unroll
  for (int q = 0; q < 4; ++q) {
    float4 al = *reinterpret_cast<const float4*>(&A_log[(size_t)d * DS2 + q * 4]);
    a[q * 4 + 0] = -__expf(al.x); a[q * 4 + 1] = -__expf(al.y);
    a[q * 4 + 2] = -__expf(al.z); a[q * 4 + 3] = -__expf(al.w);
  }
  const size_t base = (size_t)(b * NCHUNK + c) * DI + d;
#pragma unroll
  for (int q = 0; q < 4; ++q)
    *reinterpret_cast<float4*>(&h[q * 4]) =
        *reinterpret_cast<const float4*>(&Hinit[base * 16 + q * 4]);
  __syncthreads();

#pragma unroll 2
  for (int tt = 0; tt < CHUNK; ++tt) {
    float v = fmaf(sdt[tt], wdt, bdt);
    float dtv = (v > 15.f) ? v : __logf(1.f + __expf(v));
    float xv = bf2f(xc[(cb + tt) * DI + d]);
    float s = dtv * xv;
    float bb[DS2], cc[DS2];
#pragma unroll
    for (int q = 0; q < 4; ++q) {
      *reinterpret_cast<float4*>(&bb[q * 4]) =
          *reinterpret_cast<const float4*>(&sB[tt][q * 4]);
      *reinterpret_cast<float4*>(&cc[q * 4]) =
          *reinterpret_cast<const float4*>(&sC[tt][q * 4]);
    }
    float y = 0.f;
#pragma unroll
    for (int n = 0; n < DS2; ++n) {
      h[n] = fmaf(__expf(a[n] * dtv), h[n], s * bb[n]);
      y = fmaf(h[n], cc[n], y);
    }
    const size_t rr = cb + tt;
    float z = bf2f(xz[rr * 3072 + DI + d]);
    float yo = fmaf(xv, Dd, y);
    ybf[rr * DI + d] = (short)f2bf(yo * (z / (1.f + __expf(-z))));
  }
}

// ---------------- launcher -------------------------------------------------
extern "C" void kernel_launch(void* const* d_in, const int* in_sizes, int n_in,
                              void* d_out, int out_size, void* d_ws, size_t ws_size,
                              hipStream_t stream) {
  const float* x      = (const float*)d_in[0];
  const float* norm_w = (const float*)d_in[1];
  const float* w_in   = (const float*)d_in[2];
  const float* conv_w = (const float*)d_in[3];
  const float* conv_b = (const float*)d_in[4];
  const float* w_x    = (const float*)d_in[5];
  const float* w_dt   = (const float*)d_in[6];
  const float* b_dt   = (const float*)d_in[7];
  const float* A_log  = (const float*)d_in[8];
  const float* Dp     = (const float*)d_in[9];
  const float* w_out  = (const float*)d_in[10];
  float* out = (float*)d_out;

  // workspace layout
  float* ws   = (float*)d_ws;
  float* Bm   = ws;                          // 4096 x 16
  float* Cm   = Bm + (size_t)NROWS * 16;
  float* dtr  = Cm + (size_t)NROWS * 16;     // 4096
  float* hL   = dtr + NROWS;                 // B*NCHUNK*DI*16 = 3.1M
  float* Tsum = hL + (size_t)BSZ * NCHUNK * DI * 16;  // 196K
  float* wxT  = Tsum + (size_t)BSZ * NCHUNK * DI;     // 33*1536
  short* xzb  = (short*)(wxT + (size_t)33 * DI);      // 4096 x 3072 bf16
  short* xcb  = xzb + (size_t)NROWS * 2 * DI;         // 4096 x 1536 bf16
  short* xnb  = xcb + (size_t)NROWS * DI;             // 4096 x 768 bf16
  short* winT = xnb + (size_t)NROWS * DM;             // 3072 x 768 bf16
  short* woutT= winT + (size_t)2 * DI * DM;           // 768 x 1536 bf16
  short* ybf  = woutT + (size_t)DM * DI;              // 4096 x 1536 bf16
  // total ~78 MB

  rms_xn_k<<<NROWS / 4, 256, 0, stream>>>(x, norm_w, xnb);
  cvt_transpose_k<<<dim3(2 * DI / 32, DM / 32), 256, 0, stream>>>(w_in, DM, 2 * DI, winT);
  cvt_transpose_k<<<dim3(DM / 32, DI / 32), 256, 0, stream>>>(w_out, DI, DM, woutT);
  wxT_k<<<(DI * 33 + 255) / 256, 256, 0, stream>>>(w_x, wxT);

  // GEMM1: xz(bf16) = xn @ w_in   (M=4096 N=3072 K=768), 128x128 tile
  gemm_bf16<128, 128, true><<<dim3(2 * DI / 128, NROWS / 128), 256, 0, stream>>>(
      xnb, DM, winT, DM, xzb, 2 * DI, DM, nullptr, 0);

  conv_silu_k<<<(NROWS * DI) / 256, 256, 0, stream>>>(xzb, conv_w, conv_b, xcb);
  xssm_k<<<NROWS / 8, 256, 0, stream>>>(xcb, wxT, Bm, Cm, dtr);

  const int nblk = BSZ * (DI / 256) * NCHUNK;  // 768
  scan_part1<<<nblk, 256, 0, stream>>>(xcb, Bm, dtr, w_dt, b_dt, A_log, hL, Tsum);
  scan_combine_k<<<(BSZ * DI * DS2) / 256, 256, 0, stream>>>(hL, Tsum, A_log);
  scan_part3<<<nblk, 256, 0, stream>>>(xcb, xzb, ybf, Bm, Cm, dtr, w_dt, b_dt,
                                       A_log, Dp, hL);

  // GEMM3: out = x + y @ w_out   (M=4096 N=768 K=1536), 128x64 tile, 384 blk
  gemm_bf16<128, 64, false><<<dim3(DM / 64, NROWS / 128), 256, 0, stream>>>(
      ybf, DI, woutT, DI, out, DM, DI, x, DM);
}

// Round 8
// 210.060 us; speedup vs baseline: 1.0081x; 1.0081x over previous
//
#include <hip/hip_runtime.h>
#include <math.h>

// S6 (Mamba-style) block, B=2 S=2048 Dm=768 Di=1536 Ds=16 K=4.
// Round 8: GEMMs -> counted-vmcnt pipeline (T4): per K-step
//   s_barrier / STAGE(t+1) / s_waitcnt vmcnt(LOADS) / s_barrier / MFMA,
// never vmcnt(0) in-loop — tile t's loads are waited one full iteration
// after issue (latency hidden), unlike R7's __syncthreads drain which
// waited on the *just-issued* prefetch. + T5 setprio around MFMA.
// Non-GEMM kernels unchanged from Round 7.

#define DM   768
#define DI   1536
#define DS2  16
#define SEQN 2048
#define BSZ  2
#define NROWS (BSZ*SEQN)   // 4096
#define CHUNK 32
#define NCHUNK (SEQN/CHUNK) // 64

#define AS1 __attribute__((address_space(1)))
#define AS3 __attribute__((address_space(3)))

typedef short short8 __attribute__((ext_vector_type(8)));
typedef short short4v __attribute__((ext_vector_type(4)));
typedef float f32x4 __attribute__((ext_vector_type(4)));

__device__ __forceinline__ unsigned short f2bf(float f) {
  unsigned u = __builtin_bit_cast(unsigned, f);
  unsigned r = (u + 0x7FFFu + ((u >> 16) & 1u)) >> 16;   // RTNE
  return (unsigned short)r;
}
__device__ __forceinline__ float bf2f(short s) {
  unsigned u = ((unsigned)(unsigned short)s) << 16;
  return __builtin_bit_cast(float, u);
}

template<int N> __device__ __forceinline__ void waitcnt_vm() {
  if constexpr (N == 0)      asm volatile("s_waitcnt vmcnt(0)" ::: "memory");
  else if constexpr (N == 4) asm volatile("s_waitcnt vmcnt(4)" ::: "memory");
  else if constexpr (N == 6) asm volatile("s_waitcnt vmcnt(6)" ::: "memory");
  else if constexpr (N == 8) asm volatile("s_waitcnt vmcnt(8)" ::: "memory");
}

// ---------------- K1: fused rmsnorm + bf16 convert -------------------------
__global__ __launch_bounds__(256) void rms_xn_k(const float* __restrict__ x,
                                                const float* __restrict__ nw,
                                                short* __restrict__ xn) {
  int wv = threadIdx.x >> 6, lane = threadIdx.x & 63;
  int row = blockIdx.x * 4 + wv;
  const float* xr = x + (size_t)row * DM;
  float4 v[3];
  float s = 0.f;
#pragma unroll
  for (int i = 0; i < 3; ++i) {
    v[i] = *reinterpret_cast<const float4*>(&xr[(i * 64 + lane) * 4]);
    s = fmaf(v[i].x, v[i].x, s); s = fmaf(v[i].y, v[i].y, s);
    s = fmaf(v[i].z, v[i].z, s); s = fmaf(v[i].w, v[i].w, s);
  }
#pragma unroll
  for (int off = 32; off >= 1; off >>= 1) s += __shfl_xor(s, off, 64);
  float rs = rsqrtf(s * (1.f / DM) + 1e-6f);
#pragma unroll
  for (int i = 0; i < 3; ++i) {
    const float4 w = *reinterpret_cast<const float4*>(&nw[(i * 64 + lane) * 4]);
    short4v o;
    o.x = (short)f2bf(v[i].x * rs * w.x); o.y = (short)f2bf(v[i].y * rs * w.y);
    o.z = (short)f2bf(v[i].z * rs * w.z); o.w = (short)f2bf(v[i].w * rs * w.w);
    *reinterpret_cast<short4v*>(&xn[(size_t)row * DM + (i * 64 + lane) * 4]) = o;
  }
}

// ---------------- K1c: dst[c][r] = bf16(src[r][c]) (tiled transpose) -------
__global__ __launch_bounds__(256) void cvt_transpose_k(const float* __restrict__ src,
                                                       int rows, int cols,
                                                       short* __restrict__ dst) {
  __shared__ float t[32][33];
  int r0 = blockIdx.y * 32, c0 = blockIdx.x * 32;
  int tid = threadIdx.x;
  int lr = tid >> 3, lc4 = (tid & 7) * 4;
  float4 v = *reinterpret_cast<const float4*>(&src[(size_t)(r0 + lr) * cols + c0 + lc4]);
  t[lr][lc4 + 0] = v.x; t[lr][lc4 + 1] = v.y; t[lr][lc4 + 2] = v.z; t[lr][lc4 + 3] = v.w;
  __syncthreads();
  int orow = tid >> 3, oc4 = (tid & 7) * 4;
  short4v o;
  o.x = (short)f2bf(t[oc4 + 0][orow]); o.y = (short)f2bf(t[oc4 + 1][orow]);
  o.z = (short)f2bf(t[oc4 + 2][orow]); o.w = (short)f2bf(t[oc4 + 3][orow]);
  *reinterpret_cast<short4v*>(&dst[(size_t)(c0 + orow) * rows + r0 + oc4]) = o;
}

// ---------------- K1d: wxT[j][k] = wx[k][j]  (33 x 1536, f32) --------------
__global__ __launch_bounds__(256) void wxT_k(const float* __restrict__ wx,
                                             float* __restrict__ wxT) {
  int idx = blockIdx.x * 256 + threadIdx.x;
  if (idx >= DI * 33) return;
  int k = idx / 33, j = idx % 33;
  wxT[(size_t)j * DI + k] = wx[idx];
}

// ---------------- bf16 MFMA GEMM, counted-vmcnt pipeline -------------------
// C = [res +] A @ B^T.  A:[M][K] bf16, Bt:[N][K] bf16. BK=64, 4 waves (2x2).
template<int BM, int BN, bool OUTBF>
__global__ __launch_bounds__(256) void gemm_bf16(
    const short* __restrict__ A, int lda,
    const short* __restrict__ Bt, int ldb,
    void* __restrict__ Cv, int ldc, int K,
    const float* __restrict__ res, int ldr)
{
  constexpr int MI = BM / 32, NJ = BN / 32, LOADS = MI + NJ;
  __shared__ __align__(16) short As[2 * BM * 64];
  __shared__ __align__(16) short Bs[2 * BN * 64];
  const int tid = threadIdx.x;
  const int w = tid >> 6, lane = tid & 63;
  const int wr = w >> 1, wc = w & 1;
  const int m0 = blockIdx.y * BM, n0 = blockIdx.x * BN;
  const int l15 = lane & 15, l4 = lane >> 4;
  const int srow = lane >> 3;          // row within 8-row chunk
  const int skb = (lane & 7) * 8;      // k element offset (16B per lane)

  f32x4 acc[MI][NJ];
#pragma unroll
  for (int i = 0; i < MI; ++i)
#pragma unroll
    for (int j = 0; j < NJ; ++j) acc[i][j] = (f32x4){0.f, 0.f, 0.f, 0.f};

  auto STAGE = [&](int buf, int k0) {
#pragma unroll
    for (int q = 0; q < MI; ++q) {     // A: BM/8 chunks of 8 rows
      int c = w * MI + q;
      __builtin_amdgcn_global_load_lds(
          (const AS1 unsigned int*)(A + (size_t)(m0 + 8 * c + srow) * lda + k0 + skb),
          (AS3 unsigned int*)((char*)As + buf * (BM * 128) + c * 1024), 16, 0, 0);
    }
#pragma unroll
    for (int q = 0; q < NJ; ++q) {     // B: BN/8 chunks
      int c = w * NJ + q;
      __builtin_amdgcn_global_load_lds(
          (const AS1 unsigned int*)(Bt + (size_t)(n0 + 8 * c + srow) * ldb + k0 + skb),
          (AS3 unsigned int*)((char*)Bs + buf * (BN * 128) + c * 1024), 16, 0, 0);
    }
  };

  STAGE(0, 0);
  int cur = 0;
  const int NT = K / 64;
  for (int t = 0; t < NT; ++t) {
    // top barrier: all waves done ds-reading buf^1 (last read in iter t-1)
    __builtin_amdgcn_sched_barrier(0);
    __builtin_amdgcn_s_barrier();
    if (t + 1 < NT) {
      STAGE(cur ^ 1, (t + 1) * 64);    // issue next tile
      waitcnt_vm<LOADS>();             // wait tile t's loads (issued 1 iter ago)
    } else {
      waitcnt_vm<0>();                 // last tile: nothing newer in flight
    }
    __builtin_amdgcn_sched_barrier(0);
    __builtin_amdgcn_s_barrier();      // all waves see tile t resident
    __builtin_amdgcn_sched_barrier(0);
    const short* Ab = As + cur * BM * 64;
    const short* Bb = Bs + cur * BN * 64;
    __builtin_amdgcn_s_setprio(1);
#pragma unroll
    for (int kk = 0; kk < 2; ++kk) {
      short8 a[MI], b[NJ];
#pragma unroll
      for (int i = 0; i < MI; ++i)
        a[i] = *reinterpret_cast<const short8*>(
            &Ab[(wr * (BM / 2) + i * 16 + l15) * 64 + kk * 32 + l4 * 8]);
#pragma unroll
      for (int j = 0; j < NJ; ++j)
        b[j] = *reinterpret_cast<const short8*>(
            &Bb[(wc * (BN / 2) + j * 16 + l15) * 64 + kk * 32 + l4 * 8]);
#pragma unroll
      for (int i = 0; i < MI; ++i)
#pragma unroll
        for (int j = 0; j < NJ; ++j)
          acc[i][j] = __builtin_amdgcn_mfma_f32_16x16x32_bf16(a[i], b[j], acc[i][j], 0, 0, 0);
    }
    __builtin_amdgcn_s_setprio(0);
    cur ^= 1;
  }

#pragma unroll
  for (int i = 0; i < MI; ++i) {
#pragma unroll
    for (int j = 0; j < NJ; ++j) {
      int col = n0 + wc * (BN / 2) + j * 16 + l15;
#pragma unroll
      for (int r = 0; r < 4; ++r) {
        int row = m0 + wr * (BM / 2) + i * 16 + l4 * 4 + r;
        float v = acc[i][j][r];
        if constexpr (OUTBF) {
          ((short*)Cv)[(size_t)row * ldc + col] = (short)f2bf(v);
        } else {
          if (res) v += res[(size_t)row * ldr + col];
          ((float*)Cv)[(size_t)row * ldc + col] = v;
        }
      }
    }
  }
}

// ---------------- K3: depthwise causal conv(K=4) + bias + SiLU -------------
__global__ __launch_bounds__(256) void conv_silu_k(const short* __restrict__ xz,
                                                   const float* __restrict__ cw,
                                                   const float* __restrict__ cb,
                                                   short* __restrict__ xc) {
  int idx = blockIdx.x * 256 + threadIdx.x;
  int d = idx % DI;
  int bt = idx / DI;
  int t = bt & (SEQN - 1);
  float acc = cb[d];
  const float4 w4 = *reinterpret_cast<const float4*>(&cw[d * 4]);
  const float wv[4] = {w4.x, w4.y, w4.z, w4.w};
  const short* base = xz + (size_t)bt * 3072 + d;
#pragma unroll
  for (int k = 0; k < 4; ++k) {
    int tt = t + k - 3;
    if (tt >= 0) acc = fmaf(bf2f(base[(ptrdiff_t)(k - 3) * 3072]), wv[k], acc);
  }
  xc[idx] = (short)f2bf(acc / (1.f + __expf(-acc)));
}

// ---------------- K4: x_ssm = xc @ wxT^T, 2 rows/wave, vectorized ----------
__global__ __launch_bounds__(256) void xssm_k(const short* __restrict__ xc,
                                              const float* __restrict__ wxT,
                                              float* __restrict__ Bm,
                                              float* __restrict__ Cm,
                                              float* __restrict__ dtr) {
  int wv = threadIdx.x >> 6, lane = threadIdx.x & 63;
  int row0 = (blockIdx.x * 4 + wv) * 2;
  const short* xr0 = xc + (size_t)row0 * DI;
  const short* xr1 = xr0 + DI;
  float a0[33], a1[33];
#pragma unroll
  for (int j = 0; j < 33; ++j) { a0[j] = 0.f; a1[j] = 0.f; }
  for (int k0 = lane * 4; k0 < DI; k0 += 256) {
    short4v s0 = *reinterpret_cast<const short4v*>(&xr0[k0]);
    short4v s1 = *reinterpret_cast<const short4v*>(&xr1[k0]);
    float x00 = bf2f(s0.x), x01 = bf2f(s0.y), x02 = bf2f(s0.z), x03 = bf2f(s0.w);
    float x10 = bf2f(s1.x), x11 = bf2f(s1.y), x12 = bf2f(s1.z), x13 = bf2f(s1.w);
#pragma unroll
    for (int j = 0; j < 33; ++j) {
      const float4 wq = *reinterpret_cast<const float4*>(&wxT[(size_t)j * DI + k0]);
      a0[j] = fmaf(x00, wq.x, fmaf(x01, wq.y, fmaf(x02, wq.z, fmaf(x03, wq.w, a0[j]))));
      a1[j] = fmaf(x10, wq.x, fmaf(x11, wq.y, fmaf(x12, wq.z, fmaf(x13, wq.w, a1[j]))));
    }
  }
#pragma unroll
  for (int j = 0; j < 33; ++j) {
#pragma unroll
    for (int off = 32; off >= 1; off >>= 1) {
      a0[j] += __shfl_xor(a0[j], off, 64);
      a1[j] += __shfl_xor(a1[j], off, 64);
    }
  }
  if (lane == 0) {
#pragma unroll
    for (int j = 0; j < 16; ++j) Bm[(size_t)row0 * 16 + j] = a0[j];
#pragma unroll
    for (int j = 0; j < 16; ++j) Cm[(size_t)row0 * 16 + j] = a0[16 + j];
    dtr[row0] = a0[32];
#pragma unroll
    for (int j = 0; j < 16; ++j) Bm[(size_t)(row0 + 1) * 16 + j] = a1[j];
#pragma unroll
    for (int j = 0; j < 16; ++j) Cm[(size_t)(row0 + 1) * 16 + j] = a1[16 + j];
    dtr[row0 + 1] = a1[32];
  }
}

// ---------------- K5a: per-chunk local scan, thread = one d-channel --------
__global__ __launch_bounds__(256) void scan_part1(
    const short* __restrict__ xc,
    const float* __restrict__ Bm, const float* __restrict__ dtr,
    const float* __restrict__ w_dt, const float* __restrict__ b_dt,
    const float* __restrict__ A_log,
    float* __restrict__ hL, float* __restrict__ Tsum)
{
  const int blk = blockIdx.x;
  const int c  = blk % NCHUNK;
  const int db = (blk / NCHUNK) % (DI / 256);
  const int b  = blk / (NCHUNK * (DI / 256));
  const int tid = threadIdx.x;
  const int d = db * 256 + tid;
  const size_t cb = (size_t)b * SEQN + c * CHUNK;

  __shared__ float sB[CHUNK][16];
  __shared__ float sdt[CHUNK];
  if (tid < CHUNK * 4)
    reinterpret_cast<float4*>(&sB[0][0])[tid] =
        reinterpret_cast<const float4*>(&Bm[cb * 16])[tid];
  if (tid < CHUNK / 4)
    reinterpret_cast<float4*>(sdt)[tid] =
        reinterpret_cast<const float4*>(&dtr[cb])[tid];
  __syncthreads();

  const float wdt = w_dt[d], bdt = b_dt[d];
  float a[DS2], h[DS2];
#pragma unroll
  for (int q = 0; q < 4; ++q) {
    float4 al = *reinterpret_cast<const float4*>(&A_log[(size_t)d * DS2 + q * 4]);
    a[q * 4 + 0] = -__expf(al.x); a[q * 4 + 1] = -__expf(al.y);
    a[q * 4 + 2] = -__expf(al.z); a[q * 4 + 3] = -__expf(al.w);
  }
#pragma unroll
  for (int n = 0; n < DS2; ++n) h[n] = 0.f;
  float T = 0.f;

#pragma unroll 2
  for (int tt = 0; tt < CHUNK; ++tt) {
    float v = fmaf(sdt[tt], wdt, bdt);
    float dtv = (v > 15.f) ? v : __logf(1.f + __expf(v));
    T += dtv;
    float xv = bf2f(xc[(cb + tt) * DI + d]);
    float s = dtv * xv;
    float bb[DS2];
#pragma unroll
    for (int q = 0; q < 4; ++q)
      *reinterpret_cast<float4*>(&bb[q * 4]) =
          *reinterpret_cast<const float4*>(&sB[tt][q * 4]);
#pragma unroll
    for (int n = 0; n < DS2; ++n)
      h[n] = fmaf(__expf(a[n] * dtv), h[n], s * bb[n]);
  }

  const size_t base = (size_t)(b * NCHUNK + c) * DI + d;
#pragma unroll
  for (int q = 0; q < 4; ++q)
    *reinterpret_cast<float4*>(&hL[base * 16 + q * 4]) =
        *reinterpret_cast<const float4*>(&h[q * 4]);
  Tsum[base] = T;
}

// ---------------- K5b: sequential chunk-combine, in place ------------------
__global__ __launch_bounds__(256) void scan_combine_k(
    float* __restrict__ hLH, const float* __restrict__ Tsum,
    const float* __restrict__ A_log)
{
  int g = blockIdx.x * 256 + threadIdx.x;
  int n = g & 15;
  int d = (g >> 4) % DI;
  int b = g / (DI * DS2);
  const float a = -__expf(A_log[(size_t)d * DS2 + n]);
  float h = 0.f;
  for (int c = 0; c < NCHUNK; ++c) {
    size_t base = (size_t)(b * NCHUNK + c) * DI + d;
    float hl = hLH[base * 16 + n];
    float T = Tsum[base];
    float hprev = h;
    h = fmaf(__expf(a * T), h, hl);
    hLH[base * 16 + n] = hprev;
  }
}

// ---------------- K5c: replay chunk with H_init + fused epilogue -----------
__global__ __launch_bounds__(256) void scan_part3(
    const short* __restrict__ xc,
    const short* __restrict__ xz,    // read z (bf16) at cols 1536..
    short* __restrict__ ybf,
    const float* __restrict__ Bm, const float* __restrict__ Cm,
    const float* __restrict__ dtr,
    const float* __restrict__ w_dt, const float* __restrict__ b_dt,
    const float* __restrict__ A_log, const float* __restrict__ Dp,
    const float* __restrict__ Hinit)
{
  const int blk = blockIdx.x;
  const int c  = blk % NCHUNK;
  const int db = (blk / NCHUNK) % (DI / 256);
  const int b  = blk / (NCHUNK * (DI / 256));
  const int tid = threadIdx.x;
  const int d = db * 256 + tid;
  const size_t cb = (size_t)b * SEQN + c * CHUNK;

  __shared__ float sB[CHUNK][16], sC[CHUNK][16];
  __shared__ float sdt[CHUNK];
  if (tid < CHUNK * 4)
    reinterpret_cast<float4*>(&sB[0][0])[tid] =
        reinterpret_cast<const float4*>(&Bm[cb * 16])[tid];
  else if (tid < CHUNK * 8)
    reinterpret_cast<float4*>(&sC[0][0])[tid - CHUNK * 4] =
        reinterpret_cast<const float4*>(&Cm[cb * 16])[tid - CHUNK * 4];
  if (tid < CHUNK / 4)
    reinterpret_cast<float4*>(sdt)[tid] =
        reinterpret_cast<const float4*>(&dtr[cb])[tid];

  const float wdt = w_dt[d], bdt = b_dt[d];
  const float Dd = Dp[d];
  float a[DS2], h[DS2];
#pragma unroll
  for (int q = 0; q < 4; ++q) {
    float4 al = *reinterpret_cast<const float4*>(&A_log[(size_t)d * DS2 + q * 4]);
    a[q * 4 + 0] = -__expf(al.x); a[q * 4 + 1] = -__expf(al.y);
    a[q * 4 + 2] = -__expf(al.z); a[q * 4 + 3] = -__expf(al.w);
  }
  const size_t base = (size_t)(b * NCHUNK + c) * DI + d;
#pragma unroll
  for (int q = 0; q < 4; ++q)
    *reinterpret_cast<float4*>(&h[q * 4]) =
        *reinterpret_cast<const float4*>(&Hinit[base * 16 + q * 4]);
  __syncthreads();

#pragma unroll 2
  for (int tt = 0; tt < CHUNK; ++tt) {
    float v = fmaf(sdt[tt], wdt, bdt);
    float dtv = (v > 15.f) ? v : __logf(1.f + __expf(v));
    float xv = bf2f(xc[(cb + tt) * DI + d]);
    float s = dtv * xv;
    float bb[DS2], cc[DS2];
#pragma unroll
    for (int q = 0; q < 4; ++q) {
      *reinterpret_cast<float4*>(&bb[q * 4]) =
          *reinterpret_cast<const float4*>(&sB[tt][q * 4]);
      *reinterpret_cast<float4*>(&cc[q * 4]) =
          *reinterpret_cast<const float4*>(&sC[tt][q * 4]);
    }
    float y = 0.f;
#pragma unroll
    for (int n = 0; n < DS2; ++n) {
      h[n] = fmaf(__expf(a[n] * dtv), h[n], s * bb[n]);
      y = fmaf(h[n], cc[n], y);
    }
    const size_t rr = cb + tt;
    float z = bf2f(xz[rr * 3072 + DI + d]);
    float yo = fmaf(xv, Dd, y);
    ybf[rr * DI + d] = (short)f2bf(yo * (z / (1.f + __expf(-z))));
  }
}

// ---------------- launcher -------------------------------------------------
extern "C" void kernel_launch(void* const* d_in, const int* in_sizes, int n_in,
                              void* d_out, int out_size, void* d_ws, size_t ws_size,
                              hipStream_t stream) {
  const float* x      = (const float*)d_in[0];
  const float* norm_w = (const float*)d_in[1];
  const float* w_in   = (const float*)d_in[2];
  const float* conv_w = (const float*)d_in[3];
  const float* conv_b = (const float*)d_in[4];
  const float* w_x    = (const float*)d_in[5];
  const float* w_dt   = (const float*)d_in[6];
  const float* b_dt   = (const float*)d_in[7];
  const float* A_log  = (const float*)d_in[8];
  const float* Dp     = (const float*)d_in[9];
  const float* w_out  = (const float*)d_in[10];
  float* out = (float*)d_out;

  // workspace layout
  float* ws   = (float*)d_ws;
  float* Bm   = ws;                          // 4096 x 16
  float* Cm   = Bm + (size_t)NROWS * 16;
  float* dtr  = Cm + (size_t)NROWS * 16;     // 4096
  float* hL   = dtr + NROWS;                 // B*NCHUNK*DI*16 = 3.1M
  float* Tsum = hL + (size_t)BSZ * NCHUNK * DI * 16;  // 196K
  float* wxT  = Tsum + (size_t)BSZ * NCHUNK * DI;     // 33*1536
  short* xzb  = (short*)(wxT + (size_t)33 * DI);      // 4096 x 3072 bf16
  short* xcb  = xzb + (size_t)NROWS * 2 * DI;         // 4096 x 1536 bf16
  short* xnb  = xcb + (size_t)NROWS * DI;             // 4096 x 768 bf16
  short* winT = xnb + (size_t)NROWS * DM;             // 3072 x 768 bf16
  short* woutT= winT + (size_t)2 * DI * DM;           // 768 x 1536 bf16
  short* ybf  = woutT + (size_t)DM * DI;              // 4096 x 1536 bf16
  // total ~78 MB

  rms_xn_k<<<NROWS / 4, 256, 0, stream>>>(x, norm_w, xnb);
  cvt_transpose_k<<<dim3(2 * DI / 32, DM / 32), 256, 0, stream>>>(w_in, DM, 2 * DI, winT);
  cvt_transpose_k<<<dim3(DM / 32, DI / 32), 256, 0, stream>>>(w_out, DI, DM, woutT);
  wxT_k<<<(DI * 33 + 255) / 256, 256, 0, stream>>>(w_x, wxT);

  // GEMM1: xz(bf16) = xn @ w_in   (M=4096 N=3072 K=768), 128x128 tile
  gemm_bf16<128, 128, true><<<dim3(2 * DI / 128, NROWS / 128), 256, 0, stream>>>(
      xnb, DM, winT, DM, xzb, 2 * DI, DM, nullptr, 0);

  conv_silu_k<<<(NROWS * DI) / 256, 256, 0, stream>>>(xzb, conv_w, conv_b, xcb);
  xssm_k<<<NROWS / 8, 256, 0, stream>>>(xcb, wxT, Bm, Cm, dtr);

  const int nblk = BSZ * (DI / 256) * NCHUNK;  // 768
  scan_part1<<<nblk, 256, 0, stream>>>(xcb, Bm, dtr, w_dt, b_dt, A_log, hL, Tsum);
  scan_combine_k<<<(BSZ * DI * DS2) / 256, 256, 0, stream>>>(hL, Tsum, A_log);
  scan_part3<<<nblk, 256, 0, stream>>>(xcb, xzb, ybf, Bm, Cm, dtr, w_dt, b_dt,
                                       A_log, Dp, hL);

  // GEMM3: out = x + y @ w_out   (M=4096 N=768 K=1536), 128x64 tile, 384 blk
  gemm_bf16<128, 64, false><<<dim3(DM / 64, NROWS / 128), 256, 0, stream>>>(
      ybf, DI, woutT, DI, out, DM, DI, x, DM);
}

// Round 9
// 196.364 us; speedup vs baseline: 1.0784x; 1.0697x over previous
//
#include <hip/hip_runtime.h>
#include <math.h>

// S6 (Mamba-style) block, B=2 S=2048 Dm=768 Di=1536 Ds=16 K=4.
// Round 9: GEMM LDS XOR-swizzle (T2, rule #21 both-sides form).
//   R8 postmortem: SQ_LDS_BANK_CONFLICT/ds_read_b128 = 12.0 exactly —
//   fragment reads at 128B row stride were a 16-way bank conflict (the
//   real critical path; R7/R8 latency levers were aimed at the wrong pipe).
//   Fix: linear LDS dest + pre-swizzled GLOBAL source (kslot^srow) +
//   same XOR on the read side. Bitwise-identical results.
// Non-GEMM kernels unchanged from Round 8.

#define DM   768
#define DI   1536
#define DS2  16
#define SEQN 2048
#define BSZ  2
#define NROWS (BSZ*SEQN)   // 4096
#define CHUNK 32
#define NCHUNK (SEQN/CHUNK) // 64

#define AS1 __attribute__((address_space(1)))
#define AS3 __attribute__((address_space(3)))

typedef short short8 __attribute__((ext_vector_type(8)));
typedef short short4v __attribute__((ext_vector_type(4)));
typedef float f32x4 __attribute__((ext_vector_type(4)));

__device__ __forceinline__ unsigned short f2bf(float f) {
  unsigned u = __builtin_bit_cast(unsigned, f);
  unsigned r = (u + 0x7FFFu + ((u >> 16) & 1u)) >> 16;   // RTNE
  return (unsigned short)r;
}
__device__ __forceinline__ float bf2f(short s) {
  unsigned u = ((unsigned)(unsigned short)s) << 16;
  return __builtin_bit_cast(float, u);
}

template<int N> __device__ __forceinline__ void waitcnt_vm() {
  if constexpr (N == 0)      asm volatile("s_waitcnt vmcnt(0)" ::: "memory");
  else if constexpr (N == 4) asm volatile("s_waitcnt vmcnt(4)" ::: "memory");
  else if constexpr (N == 6) asm volatile("s_waitcnt vmcnt(6)" ::: "memory");
  else if constexpr (N == 8) asm volatile("s_waitcnt vmcnt(8)" ::: "memory");
}

// ---------------- K1: fused rmsnorm + bf16 convert -------------------------
__global__ __launch_bounds__(256) void rms_xn_k(const float* __restrict__ x,
                                                const float* __restrict__ nw,
                                                short* __restrict__ xn) {
  int wv = threadIdx.x >> 6, lane = threadIdx.x & 63;
  int row = blockIdx.x * 4 + wv;
  const float* xr = x + (size_t)row * DM;
  float4 v[3];
  float s = 0.f;
#pragma unroll
  for (int i = 0; i < 3; ++i) {
    v[i] = *reinterpret_cast<const float4*>(&xr[(i * 64 + lane) * 4]);
    s = fmaf(v[i].x, v[i].x, s); s = fmaf(v[i].y, v[i].y, s);
    s = fmaf(v[i].z, v[i].z, s); s = fmaf(v[i].w, v[i].w, s);
  }
#pragma unroll
  for (int off = 32; off >= 1; off >>= 1) s += __shfl_xor(s, off, 64);
  float rs = rsqrtf(s * (1.f / DM) + 1e-6f);
#pragma unroll
  for (int i = 0; i < 3; ++i) {
    const float4 w = *reinterpret_cast<const float4*>(&nw[(i * 64 + lane) * 4]);
    short4v o;
    o.x = (short)f2bf(v[i].x * rs * w.x); o.y = (short)f2bf(v[i].y * rs * w.y);
    o.z = (short)f2bf(v[i].z * rs * w.z); o.w = (short)f2bf(v[i].w * rs * w.w);
    *reinterpret_cast<short4v*>(&xn[(size_t)row * DM + (i * 64 + lane) * 4]) = o;
  }
}

// ---------------- K1c: dst[c][r] = bf16(src[r][c]) (tiled transpose) -------
__global__ __launch_bounds__(256) void cvt_transpose_k(const float* __restrict__ src,
                                                       int rows, int cols,
                                                       short* __restrict__ dst) {
  __shared__ float t[32][33];
  int r0 = blockIdx.y * 32, c0 = blockIdx.x * 32;
  int tid = threadIdx.x;
  int lr = tid >> 3, lc4 = (tid & 7) * 4;
  float4 v = *reinterpret_cast<const float4*>(&src[(size_t)(r0 + lr) * cols + c0 + lc4]);
  t[lr][lc4 + 0] = v.x; t[lr][lc4 + 1] = v.y; t[lr][lc4 + 2] = v.z; t[lr][lc4 + 3] = v.w;
  __syncthreads();
  int orow = tid >> 3, oc4 = (tid & 7) * 4;
  short4v o;
  o.x = (short)f2bf(t[oc4 + 0][orow]); o.y = (short)f2bf(t[oc4 + 1][orow]);
  o.z = (short)f2bf(t[oc4 + 2][orow]); o.w = (short)f2bf(t[oc4 + 3][orow]);
  *reinterpret_cast<short4v*>(&dst[(size_t)(c0 + orow) * rows + r0 + oc4]) = o;
}

// ---------------- K1d: wxT[j][k] = wx[k][j]  (33 x 1536, f32) --------------
__global__ __launch_bounds__(256) void wxT_k(const float* __restrict__ wx,
                                             float* __restrict__ wxT) {
  int idx = blockIdx.x * 256 + threadIdx.x;
  if (idx >= DI * 33) return;
  int k = idx / 33, j = idx % 33;
  wxT[(size_t)j * DI + k] = wx[idx];
}

// ---------------- bf16 MFMA GEMM, counted-vmcnt + LDS XOR-swizzle ----------
// C = [res +] A @ B^T.  A:[M][K] bf16, Bt:[N][K] bf16. BK=64, 4 waves (2x2).
// LDS row = 64 bf16 = 8 slots of 16B. Slot s of row r holds global slot s^r
// (staged via pre-swizzled global src; gload_lds dest is linear). Reads XOR
// the same way -> 2-way max aliasing (free) instead of 16-way conflict.
template<int BM, int BN, bool OUTBF>
__global__ __launch_bounds__(256) void gemm_bf16(
    const short* __restrict__ A, int lda,
    const short* __restrict__ Bt, int ldb,
    void* __restrict__ Cv, int ldc, int K,
    const float* __restrict__ res, int ldr)
{
  constexpr int MI = BM / 32, NJ = BN / 32, LOADS = MI + NJ;
  __shared__ __align__(16) short As[2 * BM * 64];
  __shared__ __align__(16) short Bs[2 * BN * 64];
  const int tid = threadIdx.x;
  const int w = tid >> 6, lane = tid & 63;
  const int wr = w >> 1, wc = w & 1;
  const int m0 = blockIdx.y * BM, n0 = blockIdx.x * BN;
  const int l15 = lane & 15, l4 = lane >> 4;
  const int srow = lane >> 3;                  // row within 8-row chunk
  const int ksw = (((lane & 7) ^ srow) * 8);   // pre-swizzled global k offset
  const int rx = l15 & 7;                      // read-side row XOR key

  f32x4 acc[MI][NJ];
#pragma unroll
  for (int i = 0; i < MI; ++i)
#pragma unroll
    for (int j = 0; j < NJ; ++j) acc[i][j] = (f32x4){0.f, 0.f, 0.f, 0.f};

  auto STAGE = [&](int buf, int k0) {
#pragma unroll
    for (int q = 0; q < MI; ++q) {     // A: BM/8 chunks of 8 rows
      int c = w * MI + q;
      __builtin_amdgcn_global_load_lds(
          (const AS1 unsigned int*)(A + (size_t)(m0 + 8 * c + srow) * lda + k0 + ksw),
          (AS3 unsigned int*)((char*)As + buf * (BM * 128) + c * 1024), 16, 0, 0);
    }
#pragma unroll
    for (int q = 0; q < NJ; ++q) {     // B: BN/8 chunks
      int c = w * NJ + q;
      __builtin_amdgcn_global_load_lds(
          (const AS1 unsigned int*)(Bt + (size_t)(n0 + 8 * c + srow) * ldb + k0 + ksw),
          (AS3 unsigned int*)((char*)Bs + buf * (BN * 128) + c * 1024), 16, 0, 0);
    }
  };

  STAGE(0, 0);
  int cur = 0;
  const int NT = K / 64;
  for (int t = 0; t < NT; ++t) {
    __builtin_amdgcn_sched_barrier(0);
    __builtin_amdgcn_s_barrier();      // all waves done reading buf^1
    if (t + 1 < NT) {
      STAGE(cur ^ 1, (t + 1) * 64);    // issue next tile
      waitcnt_vm<LOADS>();             // wait tile t's loads (issued 1 iter ago)
    } else {
      waitcnt_vm<0>();
    }
    __builtin_amdgcn_sched_barrier(0);
    __builtin_amdgcn_s_barrier();      // all waves see tile t resident
    __builtin_amdgcn_sched_barrier(0);
    const short* Ab = As + cur * BM * 64;
    const short* Bb = Bs + cur * BN * 64;
    __builtin_amdgcn_s_setprio(1);
#pragma unroll
    for (int kk = 0; kk < 2; ++kk) {
      short8 a[MI], b[NJ];
#pragma unroll
      for (int i = 0; i < MI; ++i)
        a[i] = *reinterpret_cast<const short8*>(
            &Ab[(wr * (BM / 2) + i * 16 + l15) * 64 + (((kk * 4 + l4) ^ rx) * 8)]);
#pragma unroll
      for (int j = 0; j < NJ; ++j)
        b[j] = *reinterpret_cast<const short8*>(
            &Bb[(wc * (BN / 2) + j * 16 + l15) * 64 + (((kk * 4 + l4) ^ rx) * 8)]);
#pragma unroll
      for (int i = 0; i < MI; ++i)
#pragma unroll
        for (int j = 0; j < NJ; ++j)
          acc[i][j] = __builtin_amdgcn_mfma_f32_16x16x32_bf16(a[i], b[j], acc[i][j], 0, 0, 0);
    }
    __builtin_amdgcn_s_setprio(0);
    cur ^= 1;
  }

#pragma unroll
  for (int i = 0; i < MI; ++i) {
#pragma unroll
    for (int j = 0; j < NJ; ++j) {
      int col = n0 + wc * (BN / 2) + j * 16 + l15;
#pragma unroll
      for (int r = 0; r < 4; ++r) {
        int row = m0 + wr * (BM / 2) + i * 16 + l4 * 4 + r;
        float v = acc[i][j][r];
        if constexpr (OUTBF) {
          ((short*)Cv)[(size_t)row * ldc + col] = (short)f2bf(v);
        } else {
          if (res) v += res[(size_t)row * ldr + col];
          ((float*)Cv)[(size_t)row * ldc + col] = v;
        }
      }
    }
  }
}

// ---------------- K3: depthwise causal conv(K=4) + bias + SiLU -------------
__global__ __launch_bounds__(256) void conv_silu_k(const short* __restrict__ xz,
                                                   const float* __restrict__ cw,
                                                   const float* __restrict__ cb,
                                                   short* __restrict__ xc) {
  int idx = blockIdx.x * 256 + threadIdx.x;
  int d = idx % DI;
  int bt = idx / DI;
  int t = bt & (SEQN - 1);
  float acc = cb[d];
  const float4 w4 = *reinterpret_cast<const float4*>(&cw[d * 4]);
  const float wv[4] = {w4.x, w4.y, w4.z, w4.w};
  const short* base = xz + (size_t)bt * 3072 + d;
#pragma unroll
  for (int k = 0; k < 4; ++k) {
    int tt = t + k - 3;
    if (tt >= 0) acc = fmaf(bf2f(base[(ptrdiff_t)(k - 3) * 3072]), wv[k], acc);
  }
  xc[idx] = (short)f2bf(acc / (1.f + __expf(-acc)));
}

// ---------------- K4: x_ssm = xc @ wxT^T, 2 rows/wave, vectorized ----------
__global__ __launch_bounds__(256) void xssm_k(const short* __restrict__ xc,
                                              const float* __restrict__ wxT,
                                              float* __restrict__ Bm,
                                              float* __restrict__ Cm,
                                              float* __restrict__ dtr) {
  int wv = threadIdx.x >> 6, lane = threadIdx.x & 63;
  int row0 = (blockIdx.x * 4 + wv) * 2;
  const short* xr0 = xc + (size_t)row0 * DI;
  const short* xr1 = xr0 + DI;
  float a0[33], a1[33];
#pragma unroll
  for (int j = 0; j < 33; ++j) { a0[j] = 0.f; a1[j] = 0.f; }
  for (int k0 = lane * 4; k0 < DI; k0 += 256) {
    short4v s0 = *reinterpret_cast<const short4v*>(&xr0[k0]);
    short4v s1 = *reinterpret_cast<const short4v*>(&xr1[k0]);
    float x00 = bf2f(s0.x), x01 = bf2f(s0.y), x02 = bf2f(s0.z), x03 = bf2f(s0.w);
    float x10 = bf2f(s1.x), x11 = bf2f(s1.y), x12 = bf2f(s1.z), x13 = bf2f(s1.w);
#pragma unroll
    for (int j = 0; j < 33; ++j) {
      const float4 wq = *reinterpret_cast<const float4*>(&wxT[(size_t)j * DI + k0]);
      a0[j] = fmaf(x00, wq.x, fmaf(x01, wq.y, fmaf(x02, wq.z, fmaf(x03, wq.w, a0[j]))));
      a1[j] = fmaf(x10, wq.x, fmaf(x11, wq.y, fmaf(x12, wq.z, fmaf(x13, wq.w, a1[j]))));
    }
  }
#pragma unroll
  for (int j = 0; j < 33; ++j) {
#pragma unroll
    for (int off = 32; off >= 1; off >>= 1) {
      a0[j] += __shfl_xor(a0[j], off, 64);
      a1[j] += __shfl_xor(a1[j], off, 64);
    }
  }
  if (lane == 0) {
#pragma unroll
    for (int j = 0; j < 16; ++j) Bm[(size_t)row0 * 16 + j] = a0[j];
#pragma unroll
    for (int j = 0; j < 16; ++j) Cm[(size_t)row0 * 16 + j] = a0[16 + j];
    dtr[row0] = a0[32];
#pragma unroll
    for (int j = 0; j < 16; ++j) Bm[(size_t)(row0 + 1) * 16 + j] = a1[j];
#pragma unroll
    for (int j = 0; j < 16; ++j) Cm[(size_t)(row0 + 1) * 16 + j] = a1[16 + j];
    dtr[row0 + 1] = a1[32];
  }
}

// ---------------- K5a: per-chunk local scan, thread = one d-channel --------
__global__ __launch_bounds__(256) void scan_part1(
    const short* __restrict__ xc,
    const float* __restrict__ Bm, const float* __restrict__ dtr,
    const float* __restrict__ w_dt, const float* __restrict__ b_dt,
    const float* __restrict__ A_log,
    float* __restrict__ hL, float* __restrict__ Tsum)
{
  const int blk = blockIdx.x;
  const int c  = blk % NCHUNK;
  const int db = (blk / NCHUNK) % (DI / 256);
  const int b  = blk / (NCHUNK * (DI / 256));
  const int tid = threadIdx.x;
  const int d = db * 256 + tid;
  const size_t cb = (size_t)b * SEQN + c * CHUNK;

  __shared__ float sB[CHUNK][16];
  __shared__ float sdt[CHUNK];
  if (tid < CHUNK * 4)
    reinterpret_cast<float4*>(&sB[0][0])[tid] =
        reinterpret_cast<const float4*>(&Bm[cb * 16])[tid];
  if (tid < CHUNK / 4)
    reinterpret_cast<float4*>(sdt)[tid] =
        reinterpret_cast<const float4*>(&dtr[cb])[tid];
  __syncthreads();

  const float wdt = w_dt[d], bdt = b_dt[d];
  float a[DS2], h[DS2];
#pragma unroll
  for (int q = 0; q < 4; ++q) {
    float4 al = *reinterpret_cast<const float4*>(&A_log[(size_t)d * DS2 + q * 4]);
    a[q * 4 + 0] = -__expf(al.x); a[q * 4 + 1] = -__expf(al.y);
    a[q * 4 + 2] = -__expf(al.z); a[q * 4 + 3] = -__expf(al.w);
  }
#pragma unroll
  for (int n = 0; n < DS2; ++n) h[n] = 0.f;
  float T = 0.f;

#pragma unroll 2
  for (int tt = 0; tt < CHUNK; ++tt) {
    float v = fmaf(sdt[tt], wdt, bdt);
    float dtv = (v > 15.f) ? v : __logf(1.f + __expf(v));
    T += dtv;
    float xv = bf2f(xc[(cb + tt) * DI + d]);
    float s = dtv * xv;
    float bb[DS2];
#pragma unroll
    for (int q = 0; q < 4; ++q)
      *reinterpret_cast<float4*>(&bb[q * 4]) =
          *reinterpret_cast<const float4*>(&sB[tt][q * 4]);
#pragma unroll
    for (int n = 0; n < DS2; ++n)
      h[n] = fmaf(__expf(a[n] * dtv), h[n], s * bb[n]);
  }

  const size_t base = (size_t)(b * NCHUNK + c) * DI + d;
#pragma unroll
  for (int q = 0; q < 4; ++q)
    *reinterpret_cast<float4*>(&hL[base * 16 + q * 4]) =
        *reinterpret_cast<const float4*>(&h[q * 4]);
  Tsum[base] = T;
}

// ---------------- K5b: sequential chunk-combine, in place ------------------
__global__ __launch_bounds__(256) void scan_combine_k(
    float* __restrict__ hLH, const float* __restrict__ Tsum,
    const float* __restrict__ A_log)
{
  int g = blockIdx.x * 256 + threadIdx.x;
  int n = g & 15;
  int d = (g >> 4) % DI;
  int b = g / (DI * DS2);
  const float a = -__expf(A_log[(size_t)d * DS2 + n]);
  float h = 0.f;
  for (int c = 0; c < NCHUNK; ++c) {
    size_t base = (size_t)(b * NCHUNK + c) * DI + d;
    float hl = hLH[base * 16 + n];
    float T = Tsum[base];
    float hprev = h;
    h = fmaf(__expf(a * T), h, hl);
    hLH[base * 16 + n] = hprev;
  }
}

// ---------------- K5c: replay chunk with H_init + fused epilogue -----------
__global__ __launch_bounds__(256) void scan_part3(
    const short* __restrict__ xc,
    const short* __restrict__ xz,    // read z (bf16) at cols 1536..
    short* __restrict__ ybf,
    const float* __restrict__ Bm, const float* __restrict__ Cm,
    const float* __restrict__ dtr,
    const float* __restrict__ w_dt, const float* __restrict__ b_dt,
    const float* __restrict__ A_log, const float* __restrict__ Dp,
    const float* __restrict__ Hinit)
{
  const int blk = blockIdx.x;
  const int c  = blk % NCHUNK;
  const int db = (blk / NCHUNK) % (DI / 256);
  const int b  = blk / (NCHUNK * (DI / 256));
  const int tid = threadIdx.x;
  const int d = db * 256 + tid;
  const size_t cb = (size_t)b * SEQN + c * CHUNK;

  __shared__ float sB[CHUNK][16], sC[CHUNK][16];
  __shared__ float sdt[CHUNK];
  if (tid < CHUNK * 4)
    reinterpret_cast<float4*>(&sB[0][0])[tid] =
        reinterpret_cast<const float4*>(&Bm[cb * 16])[tid];
  else if (tid < CHUNK * 8)
    reinterpret_cast<float4*>(&sC[0][0])[tid - CHUNK * 4] =
        reinterpret_cast<const float4*>(&Cm[cb * 16])[tid - CHUNK * 4];
  if (tid < CHUNK / 4)
    reinterpret_cast<float4*>(sdt)[tid] =
        reinterpret_cast<const float4*>(&dtr[cb])[tid];

  const float wdt = w_dt[d], bdt = b_dt[d];
  const float Dd = Dp[d];
  float a[DS2], h[DS2];
#pragma unroll
  for (int q = 0; q < 4; ++q) {
    float4 al = *reinterpret_cast<const float4*>(&A_log[(size_t)d * DS2 + q * 4]);
    a[q * 4 + 0] = -__expf(al.x); a[q * 4 + 1] = -__expf(al.y);
    a[q * 4 + 2] = -__expf(al.z); a[q * 4 + 3] = -__expf(al.w);
  }
  const size_t base = (size_t)(b * NCHUNK + c) * DI + d;
#pragma unroll
  for (int q = 0; q < 4; ++q)
    *reinterpret_cast<float4*>(&h[q * 4]) =
        *reinterpret_cast<const float4*>(&Hinit[base * 16 + q * 4]);
  __syncthreads();

#pragma unroll 2
  for (int tt = 0; tt < CHUNK; ++tt) {
    float v = fmaf(sdt[tt], wdt, bdt);
    float dtv = (v > 15.f) ? v : __logf(1.f + __expf(v));
    float xv = bf2f(xc[(cb + tt) * DI + d]);
    float s = dtv * xv;
    float bb[DS2], cc[DS2];
#pragma unroll
    for (int q = 0; q < 4; ++q) {
      *reinterpret_cast<float4*>(&bb[q * 4]) =
          *reinterpret_cast<const float4*>(&sB[tt][q * 4]);
      *reinterpret_cast<float4*>(&cc[q * 4]) =
          *reinterpret_cast<const float4*>(&sC[tt][q * 4]);
    }
    float y = 0.f;
#pragma unroll
    for (int n = 0; n < DS2; ++n) {
      h[n] = fmaf(__expf(a[n] * dtv), h[n], s * bb[n]);
      y = fmaf(h[n], cc[n], y);
    }
    const size_t rr = cb + tt;
    float z = bf2f(xz[rr * 3072 + DI + d]);
    float yo = fmaf(xv, Dd, y);
    ybf[rr * DI + d] = (short)f2bf(yo * (z / (1.f + __expf(-z))));
  }
}

// ---------------- launcher -------------------------------------------------
extern "C" void kernel_launch(void* const* d_in, const int* in_sizes, int n_in,
                              void* d_out, int out_size, void* d_ws, size_t ws_size,
                              hipStream_t stream) {
  const float* x      = (const float*)d_in[0];
  const float* norm_w = (const float*)d_in[1];
  const float* w_in   = (const float*)d_in[2];
  const float* conv_w = (const float*)d_in[3];
  const float* conv_b = (const float*)d_in[4];
  const float* w_x    = (const float*)d_in[5];
  const float* w_dt   = (const float*)d_in[6];
  const float* b_dt   = (const float*)d_in[7];
  const float* A_log  = (const float*)d_in[8];
  const float* Dp     = (const float*)d_in[9];
  const float* w_out  = (const float*)d_in[10];
  float* out = (float*)d_out;

  // workspace layout
  float* ws   = (float*)d_ws;
  float* Bm   = ws;                          // 4096 x 16
  float* Cm   = Bm + (size_t)NROWS * 16;
  float* dtr  = Cm + (size_t)NROWS * 16;     // 4096
  float* hL   = dtr + NROWS;                 // B*NCHUNK*DI*16 = 3.1M
  float* Tsum = hL + (size_t)BSZ * NCHUNK * DI * 16;  // 196K
  float* wxT  = Tsum + (size_t)BSZ * NCHUNK * DI;     // 33*1536
  short* xzb  = (short*)(wxT + (size_t)33 * DI);      // 4096 x 3072 bf16
  short* xcb  = xzb + (size_t)NROWS * 2 * DI;         // 4096 x 1536 bf16
  short* xnb  = xcb + (size_t)NROWS * DI;             // 4096 x 768 bf16
  short* winT = xnb + (size_t)NROWS * DM;             // 3072 x 768 bf16
  short* woutT= winT + (size_t)2 * DI * DM;           // 768 x 1536 bf16
  short* ybf  = woutT + (size_t)DM * DI;              // 4096 x 1536 bf16
  // total ~78 MB

  rms_xn_k<<<NROWS / 4, 256, 0, stream>>>(x, norm_w, xnb);
  cvt_transpose_k<<<dim3(2 * DI / 32, DM / 32), 256, 0, stream>>>(w_in, DM, 2 * DI, winT);
  cvt_transpose_k<<<dim3(DM / 32, DI / 32), 256, 0, stream>>>(w_out, DI, DM, woutT);
  wxT_k<<<(DI * 33 + 255) / 256, 256, 0, stream>>>(w_x, wxT);

  // GEMM1: xz(bf16) = xn @ w_in   (M=4096 N=3072 K=768), 128x128 tile
  gemm_bf16<128, 128, true><<<dim3(2 * DI / 128, NROWS / 128), 256, 0, stream>>>(
      xnb, DM, winT, DM, xzb, 2 * DI, DM, nullptr, 0);

  conv_silu_k<<<(NROWS * DI) / 256, 256, 0, stream>>>(xzb, conv_w, conv_b, xcb);
  xssm_k<<<NROWS / 8, 256, 0, stream>>>(xcb, wxT, Bm, Cm, dtr);

  const int nblk = BSZ * (DI / 256) * NCHUNK;  // 768
  scan_part1<<<nblk, 256, 0, stream>>>(xcb, Bm, dtr, w_dt, b_dt, A_log, hL, Tsum);
  scan_combine_k<<<(BSZ * DI * DS2) / 256, 256, 0, stream>>>(hL, Tsum, A_log);
  scan_part3<<<nblk, 256, 0, stream>>>(xcb, xzb, ybf, Bm, Cm, dtr, w_dt, b_dt,
                                       A_log, Dp, hL);

  // GEMM3: out = x + y @ w_out   (M=4096 N=768 K=1536), 128x64 tile, 384 blk
  gemm_bf16<128, 64, false><<<dim3(DM / 64, NROWS / 128), 256, 0, stream>>>(
      ybf, DI, woutT, DI, out, DM, DI, x, DM);
}

// Round 10
// 175.026 us; speedup vs baseline: 1.2098x; 1.1219x over previous
//
#include <hip/hip_runtime.h>
#include <math.h>

// S6 (Mamba-style) block, B=2 S=2048 Dm=768 Di=1536 Ds=16 K=4.
// Round 10: (a) GEMMs -> 8-wave (512-thread) blocks, same counted-vmcnt +
//           XOR-swizzle structure. R9 showed ~4100 cy/K-step with only
//           2 waves/SIMD — barrier/ds latency exposed by thin TLP. 8-wave
//           blocks double waves/CU (GEMM3: 49KB LDS -> 3 blocks/CU = 24 w).
//           (b) rms_xn + 2 weight transposes + wxT merged into one prep_k
//           (11 -> 8 launches).
// Other kernels unchanged from Round 9.

#define DM   768
#define DI   1536
#define DS2  16
#define SEQN 2048
#define BSZ  2
#define NROWS (BSZ*SEQN)   // 4096
#define CHUNK 32
#define NCHUNK (SEQN/CHUNK) // 64

#define AS1 __attribute__((address_space(1)))
#define AS3 __attribute__((address_space(3)))

typedef short short8 __attribute__((ext_vector_type(8)));
typedef short short4v __attribute__((ext_vector_type(4)));
typedef float f32x4 __attribute__((ext_vector_type(4)));

__device__ __forceinline__ unsigned short f2bf(float f) {
  unsigned u = __builtin_bit_cast(unsigned, f);
  unsigned r = (u + 0x7FFFu + ((u >> 16) & 1u)) >> 16;   // RTNE
  return (unsigned short)r;
}
__device__ __forceinline__ float bf2f(short s) {
  unsigned u = ((unsigned)(unsigned short)s) << 16;
  return __builtin_bit_cast(float, u);
}

template<int N> __device__ __forceinline__ void waitcnt_vm() {
  if constexpr (N == 0)      asm volatile("s_waitcnt vmcnt(0)" ::: "memory");
  else if constexpr (N == 2) asm volatile("s_waitcnt vmcnt(2)" ::: "memory");
  else if constexpr (N == 3) asm volatile("s_waitcnt vmcnt(3)" ::: "memory");
  else if constexpr (N == 4) asm volatile("s_waitcnt vmcnt(4)" ::: "memory");
  else if constexpr (N == 6) asm volatile("s_waitcnt vmcnt(6)" ::: "memory");
  else if constexpr (N == 8) asm volatile("s_waitcnt vmcnt(8)" ::: "memory");
}

// ---------------- prep_k: fused rms_xn / w_in^T / w_out^T / wxT ------------
__device__ __forceinline__ void transpose_body(const float* __restrict__ src,
                                               int rows, int cols,
                                               short* __restrict__ dst,
                                               int bx, int by, int tid) {
  __shared__ float t[32][33];
  int r0 = by * 32, c0 = bx * 32;
  int lr = tid >> 3, lc4 = (tid & 7) * 4;
  float4 v = *reinterpret_cast<const float4*>(&src[(size_t)(r0 + lr) * cols + c0 + lc4]);
  t[lr][lc4 + 0] = v.x; t[lr][lc4 + 1] = v.y; t[lr][lc4 + 2] = v.z; t[lr][lc4 + 3] = v.w;
  __syncthreads();
  int orow = tid >> 3, oc4 = (tid & 7) * 4;
  short4v o;
  o.x = (short)f2bf(t[oc4 + 0][orow]); o.y = (short)f2bf(t[oc4 + 1][orow]);
  o.z = (short)f2bf(t[oc4 + 2][orow]); o.w = (short)f2bf(t[oc4 + 3][orow]);
  *reinterpret_cast<short4v*>(&dst[(size_t)(c0 + orow) * rows + r0 + oc4]) = o;
}

__global__ __launch_bounds__(256) void prep_k(
    const float* __restrict__ x, const float* __restrict__ nw,
    short* __restrict__ xn,
    const float* __restrict__ w_in, short* __restrict__ winT,
    const float* __restrict__ w_out, short* __restrict__ woutT,
    const float* __restrict__ wx, float* __restrict__ wxT) {
  const int bid = blockIdx.x;
  const int tid = threadIdx.x;
  if (bid < 1024) {                       // rms_xn: 4 rows per block
    int wv = tid >> 6, lane = tid & 63;
    int row = bid * 4 + wv;
    const float* xr = x + (size_t)row * DM;
    float4 v[3];
    float s = 0.f;
#pragma unroll
    for (int i = 0; i < 3; ++i) {
      v[i] = *reinterpret_cast<const float4*>(&xr[(i * 64 + lane) * 4]);
      s = fmaf(v[i].x, v[i].x, s); s = fmaf(v[i].y, v[i].y, s);
      s = fmaf(v[i].z, v[i].z, s); s = fmaf(v[i].w, v[i].w, s);
    }
#pragma unroll
    for (int off = 32; off >= 1; off >>= 1) s += __shfl_xor(s, off, 64);
    float rs = rsqrtf(s * (1.f / DM) + 1e-6f);
#pragma unroll
    for (int i = 0; i < 3; ++i) {
      const float4 w = *reinterpret_cast<const float4*>(&nw[(i * 64 + lane) * 4]);
      short4v o;
      o.x = (short)f2bf(v[i].x * rs * w.x); o.y = (short)f2bf(v[i].y * rs * w.y);
      o.z = (short)f2bf(v[i].z * rs * w.z); o.w = (short)f2bf(v[i].w * rs * w.w);
      *reinterpret_cast<short4v*>(&xn[(size_t)row * DM + (i * 64 + lane) * 4]) = o;
    }
  } else if (bid < 1024 + 2304) {         // w_in^T: 96 x 24 tile grid
    int i2 = bid - 1024;
    transpose_body(w_in, DM, 2 * DI, winT, i2 % 96, i2 / 96, tid);
  } else if (bid < 1024 + 2304 + 1152) {  // w_out^T: 24 x 48 tile grid
    int i3 = bid - (1024 + 2304);
    transpose_body(w_out, DI, DM, woutT, i3 % 24, i3 / 24, tid);
  } else {                                // wxT: 33 x 1536
    int idx = (bid - (1024 + 2304 + 1152)) * 256 + tid;
    if (idx < DI * 33) {
      int k = idx / 33, j = idx % 33;
      wxT[(size_t)j * DI + k] = wx[idx];
    }
  }
}

// ---------------- bf16 MFMA GEMM, 8 waves, counted-vmcnt + XOR swizzle -----
// C = [res +] A @ B^T.  A:[M][K] bf16, Bt:[N][K] bf16. BK=64.
// 512 thr = 8 waves (2M x 4N); per-wave (BM/2)x(BN/4) output.
// Staging: (BM+BN)/8 chunks of 8 rows split 3/wave; vmcnt(3) pipeline.
// LDS slot s of row r holds global k-slot s^r (pre-swizzled source, rule #21).
template<int BM, int BN, bool OUTBF>
__global__ __launch_bounds__(512) void gemm_bf16(
    const short* __restrict__ A, int lda,
    const short* __restrict__ Bt, int ldb,
    void* __restrict__ Cv, int ldc, int K,
    const float* __restrict__ res, int ldr)
{
  constexpr int WM = BM / 2, WN = BN / 4;
  constexpr int MI = WM / 16, NJ = WN / 16;
  constexpr int ACH = BM / 8, BCH = BN / 8;
  constexpr int CPW = (ACH + BCH) / 8;       // gload_lds per wave per tile
  static_assert((ACH + BCH) % 8 == 0, "chunks must split across 8 waves");
  __shared__ __align__(16) short As[2 * BM * 64];
  __shared__ __align__(16) short Bs[2 * BN * 64];
  const int tid = threadIdx.x;
  const int w = tid >> 6, lane = tid & 63;
  const int wr = w >> 2, wc = w & 3;
  const int m0 = blockIdx.y * BM, n0 = blockIdx.x * BN;
  const int l15 = lane & 15, l4 = lane >> 4;
  const int srow = lane >> 3;                  // row within 8-row chunk
  const int ksw = (((lane & 7) ^ srow) * 8);   // pre-swizzled global k offset
  const int rx = l15 & 7;                      // read-side XOR key

  f32x4 acc[MI][NJ];
#pragma unroll
  for (int i = 0; i < MI; ++i)
#pragma unroll
    for (int j = 0; j < NJ; ++j) acc[i][j] = (f32x4){0.f, 0.f, 0.f, 0.f};

  auto STAGE = [&](int buf, int k0) {
#pragma unroll
    for (int q = 0; q < CPW; ++q) {
      int c = w * CPW + q;
      if (c < ACH) {
        __builtin_amdgcn_global_load_lds(
            (const AS1 unsigned int*)(A + (size_t)(m0 + 8 * c + srow) * lda + k0 + ksw),
            (AS3 unsigned int*)((char*)As + buf * (BM * 128) + c * 1024), 16, 0, 0);
      } else {
        int c2 = c - ACH;
        __builtin_amdgcn_global_load_lds(
            (const AS1 unsigned int*)(Bt + (size_t)(n0 + 8 * c2 + srow) * ldb + k0 + ksw),
            (AS3 unsigned int*)((char*)Bs + buf * (BN * 128) + c2 * 1024), 16, 0, 0);
      }
    }
  };

  STAGE(0, 0);
  int cur = 0;
  const int NT = K / 64;
  for (int t = 0; t < NT; ++t) {
    __builtin_amdgcn_sched_barrier(0);
    __builtin_amdgcn_s_barrier();      // all waves done reading buf^1
    if (t + 1 < NT) {
      STAGE(cur ^ 1, (t + 1) * 64);    // issue next tile
      waitcnt_vm<CPW>();               // wait tile t's loads (1 iter old)
    } else {
      waitcnt_vm<0>();
    }
    __builtin_amdgcn_sched_barrier(0);
    __builtin_amdgcn_s_barrier();      // tile t resident for all waves
    __builtin_amdgcn_sched_barrier(0);
    const short* Ab = As + cur * BM * 64;
    const short* Bb = Bs + cur * BN * 64;
    __builtin_amdgcn_s_setprio(1);
#pragma unroll
    for (int kk = 0; kk < 2; ++kk) {
      short8 a[MI], b[NJ];
#pragma unroll
      for (int i = 0; i < MI; ++i)
        a[i] = *reinterpret_cast<const short8*>(
            &Ab[(wr * WM + i * 16 + l15) * 64 + (((kk * 4 + l4) ^ rx) * 8)]);
#pragma unroll
      for (int j = 0; j < NJ; ++j)
        b[j] = *reinterpret_cast<const short8*>(
            &Bb[(wc * WN + j * 16 + l15) * 64 + (((kk * 4 + l4) ^ rx) * 8)]);
#pragma unroll
      for (int i = 0; i < MI; ++i)
#pragma unroll
        for (int j = 0; j < NJ; ++j)
          acc[i][j] = __builtin_amdgcn_mfma_f32_16x16x32_bf16(a[i], b[j], acc[i][j], 0, 0, 0);
    }
    __builtin_amdgcn_s_setprio(0);
    cur ^= 1;
  }

#pragma unroll
  for (int i = 0; i < MI; ++i) {
#pragma unroll
    for (int j = 0; j < NJ; ++j) {
      int col = n0 + wc * WN + j * 16 + l15;
#pragma unroll
      for (int r = 0; r < 4; ++r) {
        int row = m0 + wr * WM + i * 16 + l4 * 4 + r;
        float v = acc[i][j][r];
        if constexpr (OUTBF) {
          ((short*)Cv)[(size_t)row * ldc + col] = (short)f2bf(v);
        } else {
          if (res) v += res[(size_t)row * ldr + col];
          ((float*)Cv)[(size_t)row * ldc + col] = v;
        }
      }
    }
  }
}

// ---------------- K3: depthwise causal conv(K=4) + bias + SiLU -------------
__global__ __launch_bounds__(256) void conv_silu_k(const short* __restrict__ xz,
                                                   const float* __restrict__ cw,
                                                   const float* __restrict__ cb,
                                                   short* __restrict__ xc) {
  int idx = blockIdx.x * 256 + threadIdx.x;
  int d = idx % DI;
  int bt = idx / DI;
  int t = bt & (SEQN - 1);
  float acc = cb[d];
  const float4 w4 = *reinterpret_cast<const float4*>(&cw[d * 4]);
  const float wv[4] = {w4.x, w4.y, w4.z, w4.w};
  const short* base = xz + (size_t)bt * 3072 + d;
#pragma unroll
  for (int k = 0; k < 4; ++k) {
    int tt = t + k - 3;
    if (tt >= 0) acc = fmaf(bf2f(base[(ptrdiff_t)(k - 3) * 3072]), wv[k], acc);
  }
  xc[idx] = (short)f2bf(acc / (1.f + __expf(-acc)));
}

// ---------------- K4: x_ssm = xc @ wxT^T, 2 rows/wave, vectorized ----------
__global__ __launch_bounds__(256) void xssm_k(const short* __restrict__ xc,
                                              const float* __restrict__ wxT,
                                              float* __restrict__ Bm,
                                              float* __restrict__ Cm,
                                              float* __restrict__ dtr) {
  int wv = threadIdx.x >> 6, lane = threadIdx.x & 63;
  int row0 = (blockIdx.x * 4 + wv) * 2;
  const short* xr0 = xc + (size_t)row0 * DI;
  const short* xr1 = xr0 + DI;
  float a0[33], a1[33];
#pragma unroll
  for (int j = 0; j < 33; ++j) { a0[j] = 0.f; a1[j] = 0.f; }
  for (int k0 = lane * 4; k0 < DI; k0 += 256) {
    short4v s0 = *reinterpret_cast<const short4v*>(&xr0[k0]);
    short4v s1 = *reinterpret_cast<const short4v*>(&xr1[k0]);
    float x00 = bf2f(s0.x), x01 = bf2f(s0.y), x02 = bf2f(s0.z), x03 = bf2f(s0.w);
    float x10 = bf2f(s1.x), x11 = bf2f(s1.y), x12 = bf2f(s1.z), x13 = bf2f(s1.w);
#pragma unroll
    for (int j = 0; j < 33; ++j) {
      const float4 wq = *reinterpret_cast<const float4*>(&wxT[(size_t)j * DI + k0]);
      a0[j] = fmaf(x00, wq.x, fmaf(x01, wq.y, fmaf(x02, wq.z, fmaf(x03, wq.w, a0[j]))));
      a1[j] = fmaf(x10, wq.x, fmaf(x11, wq.y, fmaf(x12, wq.z, fmaf(x13, wq.w, a1[j]))));
    }
  }
#pragma unroll
  for (int j = 0; j < 33; ++j) {
#pragma unroll
    for (int off = 32; off >= 1; off >>= 1) {
      a0[j] += __shfl_xor(a0[j], off, 64);
      a1[j] += __shfl_xor(a1[j], off, 64);
    }
  }
  if (lane == 0) {
#pragma unroll
    for (int j = 0; j < 16; ++j) Bm[(size_t)row0 * 16 + j] = a0[j];
#pragma unroll
    for (int j = 0; j < 16; ++j) Cm[(size_t)row0 * 16 + j] = a0[16 + j];
    dtr[row0] = a0[32];
#pragma unroll
    for (int j = 0; j < 16; ++j) Bm[(size_t)(row0 + 1) * 16 + j] = a1[j];
#pragma unroll
    for (int j = 0; j < 16; ++j) Cm[(size_t)(row0 + 1) * 16 + j] = a1[16 + j];
    dtr[row0 + 1] = a1[32];
  }
}

// ---------------- K5a: per-chunk local scan, thread = one d-channel --------
__global__ __launch_bounds__(256) void scan_part1(
    const short* __restrict__ xc,
    const float* __restrict__ Bm, const float* __restrict__ dtr,
    const float* __restrict__ w_dt, const float* __restrict__ b_dt,
    const float* __restrict__ A_log,
    float* __restrict__ hL, float* __restrict__ Tsum)
{
  const int blk = blockIdx.x;
  const int c  = blk % NCHUNK;
  const int db = (blk / NCHUNK) % (DI / 256);
  const int b  = blk / (NCHUNK * (DI / 256));
  const int tid = threadIdx.x;
  const int d = db * 256 + tid;
  const size_t cb = (size_t)b * SEQN + c * CHUNK;

  __shared__ float sB[CHUNK][16];
  __shared__ float sdt[CHUNK];
  if (tid < CHUNK * 4)
    reinterpret_cast<float4*>(&sB[0][0])[tid] =
        reinterpret_cast<const float4*>(&Bm[cb * 16])[tid];
  if (tid < CHUNK / 4)
    reinterpret_cast<float4*>(sdt)[tid] =
        reinterpret_cast<const float4*>(&dtr[cb])[tid];
  __syncthreads();

  const float wdt = w_dt[d], bdt = b_dt[d];
  float a[DS2], h[DS2];
#pragma unroll
  for (int q = 0; q < 4; ++q) {
    float4 al = *reinterpret_cast<const float4*>(&A_log[(size_t)d * DS2 + q * 4]);
    a[q * 4 + 0] = -__expf(al.x); a[q * 4 + 1] = -__expf(al.y);
    a[q * 4 + 2] = -__expf(al.z); a[q * 4 + 3] = -__expf(al.w);
  }
#pragma unroll
  for (int n = 0; n < DS2; ++n) h[n] = 0.f;
  float T = 0.f;

#pragma unroll 2
  for (int tt = 0; tt < CHUNK; ++tt) {
    float v = fmaf(sdt[tt], wdt, bdt);
    float dtv = (v > 15.f) ? v : __logf(1.f + __expf(v));
    T += dtv;
    float xv = bf2f(xc[(cb + tt) * DI + d]);
    float s = dtv * xv;
    float bb[DS2];
#pragma unroll
    for (int q = 0; q < 4; ++q)
      *reinterpret_cast<float4*>(&bb[q * 4]) =
          *reinterpret_cast<const float4*>(&sB[tt][q * 4]);
#pragma unroll
    for (int n = 0; n < DS2; ++n)
      h[n] = fmaf(__expf(a[n] * dtv), h[n], s * bb[n]);
  }

  const size_t base = (size_t)(b * NCHUNK + c) * DI + d;
#pragma unroll
  for (int q = 0; q < 4; ++q)
    *reinterpret_cast<float4*>(&hL[base * 16 + q * 4]) =
        *reinterpret_cast<const float4*>(&h[q * 4]);
  Tsum[base] = T;
}

// ---------------- K5b: sequential chunk-combine, in place ------------------
__global__ __launch_bounds__(256) void scan_combine_k(
    float* __restrict__ hLH, const float* __restrict__ Tsum,
    const float* __restrict__ A_log)
{
  int g = blockIdx.x * 256 + threadIdx.x;
  int n = g & 15;
  int d = (g >> 4) % DI;
  int b = g / (DI * DS2);
  const float a = -__expf(A_log[(size_t)d * DS2 + n]);
  float h = 0.f;
  for (int c = 0; c < NCHUNK; ++c) {
    size_t base = (size_t)(b * NCHUNK + c) * DI + d;
    float hl = hLH[base * 16 + n];
    float T = Tsum[base];
    float hprev = h;
    h = fmaf(__expf(a * T), h, hl);
    hLH[base * 16 + n] = hprev;
  }
}

// ---------------- K5c: replay chunk with H_init + fused epilogue -----------
__global__ __launch_bounds__(256) void scan_part3(
    const short* __restrict__ xc,
    const short* __restrict__ xz,    // read z (bf16) at cols 1536..
    short* __restrict__ ybf,
    const float* __restrict__ Bm, const float* __restrict__ Cm,
    const float* __restrict__ dtr,
    const float* __restrict__ w_dt, const float* __restrict__ b_dt,
    const float* __restrict__ A_log, const float* __restrict__ Dp,
    const float* __restrict__ Hinit)
{
  const int blk = blockIdx.x;
  const int c  = blk % NCHUNK;
  const int db = (blk / NCHUNK) % (DI / 256);
  const int b  = blk / (NCHUNK * (DI / 256));
  const int tid = threadIdx.x;
  const int d = db * 256 + tid;
  const size_t cb = (size_t)b * SEQN + c * CHUNK;

  __shared__ float sB[CHUNK][16], sC[CHUNK][16];
  __shared__ float sdt[CHUNK];
  if (tid < CHUNK * 4)
    reinterpret_cast<float4*>(&sB[0][0])[tid] =
        reinterpret_cast<const float4*>(&Bm[cb * 16])[tid];
  else if (tid < CHUNK * 8)
    reinterpret_cast<float4*>(&sC[0][0])[tid - CHUNK * 4] =
        reinterpret_cast<const float4*>(&Cm[cb * 16])[tid - CHUNK * 4];
  if (tid < CHUNK / 4)
    reinterpret_cast<float4*>(sdt)[tid] =
        reinterpret_cast<const float4*>(&dtr[cb])[tid];

  const float wdt = w_dt[d], bdt = b_dt[d];
  const float Dd = Dp[d];
  float a[DS2], h[DS2];
#pragma unroll
  for (int q = 0; q < 4; ++q) {
    float4 al = *reinterpret_cast<const float4*>(&A_log[(size_t)d * DS2 + q * 4]);
    a[q * 4 + 0] = -__expf(al.x); a[q * 4 + 1] = -__expf(al.y);
    a[q * 4 + 2] = -__expf(al.z); a[q * 4 + 3] = -__expf(al.w);
  }
  const size_t base = (size_t)(b * NCHUNK + c) * DI + d;
#pragma unroll
  for (int q = 0; q < 4; ++q)
    *reinterpret_cast<float4*>(&h[q * 4]) =
        *reinterpret_cast<const float4*>(&Hinit[base * 16 + q * 4]);
  __syncthreads();

#pragma unroll 2
  for (int tt = 0; tt < CHUNK; ++tt) {
    float v = fmaf(sdt[tt], wdt, bdt);
    float dtv = (v > 15.f) ? v : __logf(1.f + __expf(v));
    float xv = bf2f(xc[(cb + tt) * DI + d]);
    float s = dtv * xv;
    float bb[DS2], cc[DS2];
#pragma unroll
    for (int q = 0; q < 4; ++q) {
      *reinterpret_cast<float4*>(&bb[q * 4]) =
          *reinterpret_cast<const float4*>(&sB[tt][q * 4]);
      *reinterpret_cast<float4*>(&cc[q * 4]) =
          *reinterpret_cast<const float4*>(&sC[tt][q * 4]);
    }
    float y = 0.f;
#pragma unroll
    for (int n = 0; n < DS2; ++n) {
      h[n] = fmaf(__expf(a[n] * dtv), h[n], s * bb[n]);
      y = fmaf(h[n], cc[n], y);
    }
    const size_t rr = cb + tt;
    float z = bf2f(xz[rr * 3072 + DI + d]);
    float yo = fmaf(xv, Dd, y);
    ybf[rr * DI + d] = (short)f2bf(yo * (z / (1.f + __expf(-z))));
  }
}

// ---------------- launcher -------------------------------------------------
extern "C" void kernel_launch(void* const* d_in, const int* in_sizes, int n_in,
                              void* d_out, int out_size, void* d_ws, size_t ws_size,
                              hipStream_t stream) {
  const float* x      = (const float*)d_in[0];
  const float* norm_w = (const float*)d_in[1];
  const float* w_in   = (const float*)d_in[2];
  const float* conv_w = (const float*)d_in[3];
  const float* conv_b = (const float*)d_in[4];
  const float* w_x    = (const float*)d_in[5];
  const float* w_dt   = (const float*)d_in[6];
  const float* b_dt   = (const float*)d_in[7];
  const float* A_log  = (const float*)d_in[8];
  const float* Dp     = (const float*)d_in[9];
  const float* w_out  = (const float*)d_in[10];
  float* out = (float*)d_out;

  // workspace layout
  float* ws   = (float*)d_ws;
  float* Bm   = ws;                          // 4096 x 16
  float* Cm   = Bm + (size_t)NROWS * 16;
  float* dtr  = Cm + (size_t)NROWS * 16;     // 4096
  float* hL   = dtr + NROWS;                 // B*NCHUNK*DI*16 = 3.1M
  float* Tsum = hL + (size_t)BSZ * NCHUNK * DI * 16;  // 196K
  float* wxT  = Tsum + (size_t)BSZ * NCHUNK * DI;     // 33*1536
  short* xzb  = (short*)(wxT + (size_t)33 * DI);      // 4096 x 3072 bf16
  short* xcb  = xzb + (size_t)NROWS * 2 * DI;         // 4096 x 1536 bf16
  short* xnb  = xcb + (size_t)NROWS * DI;             // 4096 x 768 bf16
  short* winT = xnb + (size_t)NROWS * DM;             // 3072 x 768 bf16
  short* woutT= winT + (size_t)2 * DI * DM;           // 768 x 1536 bf16
  short* ybf  = woutT + (size_t)DM * DI;              // 4096 x 1536 bf16
  // total ~78 MB

  // prep: rms_xn (1024) + w_in^T (2304) + w_out^T (1152) + wxT (198)
  prep_k<<<1024 + 2304 + 1152 + 198, 256, 0, stream>>>(
      x, norm_w, xnb, w_in, winT, w_out, woutT, w_x, wxT);

  // GEMM1: xz(bf16) = xn @ w_in   (M=4096 N=3072 K=768), 128x128, 8 waves
  gemm_bf16<128, 128, true><<<dim3(2 * DI / 128, NROWS / 128), 512, 0, stream>>>(
      xnb, DM, winT, DM, xzb, 2 * DI, DM, nullptr, 0);

  conv_silu_k<<<(NROWS * DI) / 256, 256, 0, stream>>>(xzb, conv_w, conv_b, xcb);
  xssm_k<<<NROWS / 8, 256, 0, stream>>>(xcb, wxT, Bm, Cm, dtr);

  const int nblk = BSZ * (DI / 256) * NCHUNK;  // 768
  scan_part1<<<nblk, 256, 0, stream>>>(xcb, Bm, dtr, w_dt, b_dt, A_log, hL, Tsum);
  scan_combine_k<<<(BSZ * DI * DS2) / 256, 256, 0, stream>>>(hL, Tsum, A_log);
  scan_part3<<<nblk, 256, 0, stream>>>(xcb, xzb, ybf, Bm, Cm, dtr, w_dt, b_dt,
                                       A_log, Dp, hL);

  // GEMM3: out = x + y @ w_out   (M=4096 N=768 K=1536), 128x64, 8 waves
  gemm_bf16<128, 64, false><<<dim3(DM / 64, NROWS / 128), 512, 0, stream>>>(
      ybf, DI, woutT, DI, out, DM, DI, x, DM);
}

// Round 11
// 157.255 us; speedup vs baseline: 1.3465x; 1.1130x over previous
//
#include <hip/hip_runtime.h>
#include <math.h>

// S6 (Mamba-style) block, B=2 S=2048 Dm=768 Di=1536 Ds=16 K=4.
// Round 11: conv_silu + xssm fused into conv_xssm_k — wave owns 2 rows,
//           loads 5 xz time-rows once, conv+SiLU in registers, stores xc,
//           then the w_x matvec runs on the (bf16-rounded) register values.
//           Kills xssm's 12.6MB xc re-read + one launch. Matvec input is
//           bf2f(f2bf(conv)) == old xc value -> bitwise-identical results.
// GEMMs (8-wave counted-vmcnt + XOR swizzle) and scan unchanged from R10.

#define DM   768
#define DI   1536
#define DS2  16
#define SEQN 2048
#define BSZ  2
#define NROWS (BSZ*SEQN)   // 4096
#define CHUNK 32
#define NCHUNK (SEQN/CHUNK) // 64

#define AS1 __attribute__((address_space(1)))
#define AS3 __attribute__((address_space(3)))

typedef short short8 __attribute__((ext_vector_type(8)));
typedef short short4v __attribute__((ext_vector_type(4)));
typedef float f32x4 __attribute__((ext_vector_type(4)));

__device__ __forceinline__ unsigned short f2bf(float f) {
  unsigned u = __builtin_bit_cast(unsigned, f);
  unsigned r = (u + 0x7FFFu + ((u >> 16) & 1u)) >> 16;   // RTNE
  return (unsigned short)r;
}
__device__ __forceinline__ float bf2f(short s) {
  unsigned u = ((unsigned)(unsigned short)s) << 16;
  return __builtin_bit_cast(float, u);
}

template<int N> __device__ __forceinline__ void waitcnt_vm() {
  if constexpr (N == 0)      asm volatile("s_waitcnt vmcnt(0)" ::: "memory");
  else if constexpr (N == 2) asm volatile("s_waitcnt vmcnt(2)" ::: "memory");
  else if constexpr (N == 3) asm volatile("s_waitcnt vmcnt(3)" ::: "memory");
  else if constexpr (N == 4) asm volatile("s_waitcnt vmcnt(4)" ::: "memory");
  else if constexpr (N == 6) asm volatile("s_waitcnt vmcnt(6)" ::: "memory");
  else if constexpr (N == 8) asm volatile("s_waitcnt vmcnt(8)" ::: "memory");
}

// ---------------- prep_k: fused rms_xn / w_in^T / w_out^T / wxT ------------
__device__ __forceinline__ void transpose_body(const float* __restrict__ src,
                                               int rows, int cols,
                                               short* __restrict__ dst,
                                               int bx, int by, int tid) {
  __shared__ float t[32][33];
  int r0 = by * 32, c0 = bx * 32;
  int lr = tid >> 3, lc4 = (tid & 7) * 4;
  float4 v = *reinterpret_cast<const float4*>(&src[(size_t)(r0 + lr) * cols + c0 + lc4]);
  t[lr][lc4 + 0] = v.x; t[lr][lc4 + 1] = v.y; t[lr][lc4 + 2] = v.z; t[lr][lc4 + 3] = v.w;
  __syncthreads();
  int orow = tid >> 3, oc4 = (tid & 7) * 4;
  short4v o;
  o.x = (short)f2bf(t[oc4 + 0][orow]); o.y = (short)f2bf(t[oc4 + 1][orow]);
  o.z = (short)f2bf(t[oc4 + 2][orow]); o.w = (short)f2bf(t[oc4 + 3][orow]);
  *reinterpret_cast<short4v*>(&dst[(size_t)(c0 + orow) * rows + r0 + oc4]) = o;
}

__global__ __launch_bounds__(256) void prep_k(
    const float* __restrict__ x, const float* __restrict__ nw,
    short* __restrict__ xn,
    const float* __restrict__ w_in, short* __restrict__ winT,
    const float* __restrict__ w_out, short* __restrict__ woutT,
    const float* __restrict__ wx, float* __restrict__ wxT) {
  const int bid = blockIdx.x;
  const int tid = threadIdx.x;
  if (bid < 1024) {                       // rms_xn: 4 rows per block
    int wv = tid >> 6, lane = tid & 63;
    int row = bid * 4 + wv;
    const float* xr = x + (size_t)row * DM;
    float4 v[3];
    float s = 0.f;
#pragma unroll
    for (int i = 0; i < 3; ++i) {
      v[i] = *reinterpret_cast<const float4*>(&xr[(i * 64 + lane) * 4]);
      s = fmaf(v[i].x, v[i].x, s); s = fmaf(v[i].y, v[i].y, s);
      s = fmaf(v[i].z, v[i].z, s); s = fmaf(v[i].w, v[i].w, s);
    }
#pragma unroll
    for (int off = 32; off >= 1; off >>= 1) s += __shfl_xor(s, off, 64);
    float rs = rsqrtf(s * (1.f / DM) + 1e-6f);
#pragma unroll
    for (int i = 0; i < 3; ++i) {
      const float4 w = *reinterpret_cast<const float4*>(&nw[(i * 64 + lane) * 4]);
      short4v o;
      o.x = (short)f2bf(v[i].x * rs * w.x); o.y = (short)f2bf(v[i].y * rs * w.y);
      o.z = (short)f2bf(v[i].z * rs * w.z); o.w = (short)f2bf(v[i].w * rs * w.w);
      *reinterpret_cast<short4v*>(&xn[(size_t)row * DM + (i * 64 + lane) * 4]) = o;
    }
  } else if (bid < 1024 + 2304) {         // w_in^T: 96 x 24 tile grid
    int i2 = bid - 1024;
    transpose_body(w_in, DM, 2 * DI, winT, i2 % 96, i2 / 96, tid);
  } else if (bid < 1024 + 2304 + 1152) {  // w_out^T: 24 x 48 tile grid
    int i3 = bid - (1024 + 2304);
    transpose_body(w_out, DI, DM, woutT, i3 % 24, i3 / 24, tid);
  } else {                                // wxT: 33 x 1536
    int idx = (bid - (1024 + 2304 + 1152)) * 256 + tid;
    if (idx < DI * 33) {
      int k = idx / 33, j = idx % 33;
      wxT[(size_t)j * DI + k] = wx[idx];
    }
  }
}

// ---------------- bf16 MFMA GEMM, 8 waves, counted-vmcnt + XOR swizzle -----
template<int BM, int BN, bool OUTBF>
__global__ __launch_bounds__(512) void gemm_bf16(
    const short* __restrict__ A, int lda,
    const short* __restrict__ Bt, int ldb,
    void* __restrict__ Cv, int ldc, int K,
    const float* __restrict__ res, int ldr)
{
  constexpr int WM = BM / 2, WN = BN / 4;
  constexpr int MI = WM / 16, NJ = WN / 16;
  constexpr int ACH = BM / 8, BCH = BN / 8;
  constexpr int CPW = (ACH + BCH) / 8;
  static_assert((ACH + BCH) % 8 == 0, "chunks must split across 8 waves");
  __shared__ __align__(16) short As[2 * BM * 64];
  __shared__ __align__(16) short Bs[2 * BN * 64];
  const int tid = threadIdx.x;
  const int w = tid >> 6, lane = tid & 63;
  const int wr = w >> 2, wc = w & 3;
  const int m0 = blockIdx.y * BM, n0 = blockIdx.x * BN;
  const int l15 = lane & 15, l4 = lane >> 4;
  const int srow = lane >> 3;
  const int ksw = (((lane & 7) ^ srow) * 8);
  const int rx = l15 & 7;

  f32x4 acc[MI][NJ];
#pragma unroll
  for (int i = 0; i < MI; ++i)
#pragma unroll
    for (int j = 0; j < NJ; ++j) acc[i][j] = (f32x4){0.f, 0.f, 0.f, 0.f};

  auto STAGE = [&](int buf, int k0) {
#pragma unroll
    for (int q = 0; q < CPW; ++q) {
      int c = w * CPW + q;
      if (c < ACH) {
        __builtin_amdgcn_global_load_lds(
            (const AS1 unsigned int*)(A + (size_t)(m0 + 8 * c + srow) * lda + k0 + ksw),
            (AS3 unsigned int*)((char*)As + buf * (BM * 128) + c * 1024), 16, 0, 0);
      } else {
        int c2 = c - ACH;
        __builtin_amdgcn_global_load_lds(
            (const AS1 unsigned int*)(Bt + (size_t)(n0 + 8 * c2 + srow) * ldb + k0 + ksw),
            (AS3 unsigned int*)((char*)Bs + buf * (BN * 128) + c2 * 1024), 16, 0, 0);
      }
    }
  };

  STAGE(0, 0);
  int cur = 0;
  const int NT = K / 64;
  for (int t = 0; t < NT; ++t) {
    __builtin_amdgcn_sched_barrier(0);
    __builtin_amdgcn_s_barrier();
    if (t + 1 < NT) {
      STAGE(cur ^ 1, (t + 1) * 64);
      waitcnt_vm<CPW>();
    } else {
      waitcnt_vm<0>();
    }
    __builtin_amdgcn_sched_barrier(0);
    __builtin_amdgcn_s_barrier();
    __builtin_amdgcn_sched_barrier(0);
    const short* Ab = As + cur * BM * 64;
    const short* Bb = Bs + cur * BN * 64;
    __builtin_amdgcn_s_setprio(1);
#pragma unroll
    for (int kk = 0; kk < 2; ++kk) {
      short8 a[MI], b[NJ];
#pragma unroll
      for (int i = 0; i < MI; ++i)
        a[i] = *reinterpret_cast<const short8*>(
            &Ab[(wr * WM + i * 16 + l15) * 64 + (((kk * 4 + l4) ^ rx) * 8)]);
#pragma unroll
      for (int j = 0; j < NJ; ++j)
        b[j] = *reinterpret_cast<const short8*>(
            &Bb[(wc * WN + j * 16 + l15) * 64 + (((kk * 4 + l4) ^ rx) * 8)]);
#pragma unroll
      for (int i = 0; i < MI; ++i)
#pragma unroll
        for (int j = 0; j < NJ; ++j)
          acc[i][j] = __builtin_amdgcn_mfma_f32_16x16x32_bf16(a[i], b[j], acc[i][j], 0, 0, 0);
    }
    __builtin_amdgcn_s_setprio(0);
    cur ^= 1;
  }

#pragma unroll
  for (int i = 0; i < MI; ++i) {
#pragma unroll
    for (int j = 0; j < NJ; ++j) {
      int col = n0 + wc * WN + j * 16 + l15;
#pragma unroll
      for (int r = 0; r < 4; ++r) {
        int row = m0 + wr * WM + i * 16 + l4 * 4 + r;
        float v = acc[i][j][r];
        if constexpr (OUTBF) {
          ((short*)Cv)[(size_t)row * ldc + col] = (short)f2bf(v);
        } else {
          if (res) v += res[(size_t)row * ldr + col];
          ((float*)Cv)[(size_t)row * ldc + col] = v;
        }
      }
    }
  }
}

// ---------------- K3+K4 fused: conv+SiLU -> xc store + x_ssm matvec --------
// 512 blocks x 256 thr; wave wv owns rows r0=blk*8+wv*2, r0+1 (same batch).
// Per k-group (short4v): load 5 xz time-rows, conv both rows, silu, round
// to bf16 (store xc), matvec on the rounded values (== old xssm input).
__global__ __launch_bounds__(256) void conv_xssm_k(
    const short* __restrict__ xz,
    const float* __restrict__ cw, const float* __restrict__ cb,
    const float* __restrict__ wxT,
    short* __restrict__ xc,
    float* __restrict__ Bm, float* __restrict__ Cm, float* __restrict__ dtr)
{
  const int wv = threadIdx.x >> 6, lane = threadIdx.x & 63;
  const int r0 = blockIdx.x * 8 + wv * 2;      // rows r0, r0+1
  const int t0 = r0 & (SEQN - 1);
  float a0[33], a1[33];
#pragma unroll
  for (int j = 0; j < 33; ++j) { a0[j] = 0.f; a1[j] = 0.f; }

  for (int it = 0; it < 6; ++it) {
    const int k0 = lane * 4 + it * 256;
    // load 5 time rows (t0-3 .. t0+1); zero rows before batch start
    short4v rb[5];
#pragma unroll
    for (int rr = 0; rr < 5; ++rr) {
      int trow = t0 - 3 + rr;
      if (trow >= 0)
        rb[rr] = *reinterpret_cast<const short4v*>(&xz[(size_t)(r0 - 3 + rr) * 3072 + k0]);
      else
        rb[rr] = (short4v){0, 0, 0, 0};
    }
    const float4 bias = *reinterpret_cast<const float4*>(&cb[k0]);
    float x0v[4], x1v[4];
    short4v o0, o1;
#pragma unroll
    for (int i = 0; i < 4; ++i) {
      const float4 cwv = *reinterpret_cast<const float4*>(&cw[(size_t)(k0 + i) * 4]);
      const float bi = (i == 0) ? bias.x : (i == 1) ? bias.y : (i == 2) ? bias.z : bias.w;
      float acc0 = bi, acc1 = bi;
      acc0 = fmaf(bf2f(rb[0][i]), cwv.x, acc0);
      acc0 = fmaf(bf2f(rb[1][i]), cwv.y, acc0);
      acc0 = fmaf(bf2f(rb[2][i]), cwv.z, acc0);
      acc0 = fmaf(bf2f(rb[3][i]), cwv.w, acc0);
      acc1 = fmaf(bf2f(rb[1][i]), cwv.x, acc1);
      acc1 = fmaf(bf2f(rb[2][i]), cwv.y, acc1);
      acc1 = fmaf(bf2f(rb[3][i]), cwv.z, acc1);
      acc1 = fmaf(bf2f(rb[4][i]), cwv.w, acc1);
      float s0 = acc0 / (1.f + __expf(-acc0));
      float s1 = acc1 / (1.f + __expf(-acc1));
      short u0 = (short)f2bf(s0), u1 = (short)f2bf(s1);
      o0[i] = u0; o1[i] = u1;
      x0v[i] = bf2f(u0); x1v[i] = bf2f(u1);   // rounded == old xc value
    }
    *reinterpret_cast<short4v*>(&xc[(size_t)r0 * DI + k0]) = o0;
    *reinterpret_cast<short4v*>(&xc[(size_t)(r0 + 1) * DI + k0]) = o1;
#pragma unroll
    for (int j = 0; j < 33; ++j) {
      const float4 wq = *reinterpret_cast<const float4*>(&wxT[(size_t)j * DI + k0]);
      a0[j] = fmaf(x0v[0], wq.x, fmaf(x0v[1], wq.y, fmaf(x0v[2], wq.z, fmaf(x0v[3], wq.w, a0[j]))));
      a1[j] = fmaf(x1v[0], wq.x, fmaf(x1v[1], wq.y, fmaf(x1v[2], wq.z, fmaf(x1v[3], wq.w, a1[j]))));
    }
  }
#pragma unroll
  for (int j = 0; j < 33; ++j) {
#pragma unroll
    for (int off = 32; off >= 1; off >>= 1) {
      a0[j] += __shfl_xor(a0[j], off, 64);
      a1[j] += __shfl_xor(a1[j], off, 64);
    }
  }
  if (lane == 0) {
#pragma unroll
    for (int j = 0; j < 16; ++j) Bm[(size_t)r0 * 16 + j] = a0[j];
#pragma unroll
    for (int j = 0; j < 16; ++j) Cm[(size_t)r0 * 16 + j] = a0[16 + j];
    dtr[r0] = a0[32];
#pragma unroll
    for (int j = 0; j < 16; ++j) Bm[(size_t)(r0 + 1) * 16 + j] = a1[j];
#pragma unroll
    for (int j = 0; j < 16; ++j) Cm[(size_t)(r0 + 1) * 16 + j] = a1[16 + j];
    dtr[r0 + 1] = a1[32];
  }
}

// ---------------- K5a: per-chunk local scan, thread = one d-channel --------
__global__ __launch_bounds__(256) void scan_part1(
    const short* __restrict__ xc,
    const float* __restrict__ Bm, const float* __restrict__ dtr,
    const float* __restrict__ w_dt, const float* __restrict__ b_dt,
    const float* __restrict__ A_log,
    float* __restrict__ hL, float* __restrict__ Tsum)
{
  const int blk = blockIdx.x;
  const int c  = blk % NCHUNK;
  const int db = (blk / NCHUNK) % (DI / 256);
  const int b  = blk / (NCHUNK * (DI / 256));
  const int tid = threadIdx.x;
  const int d = db * 256 + tid;
  const size_t cb = (size_t)b * SEQN + c * CHUNK;

  __shared__ float sB[CHUNK][16];
  __shared__ float sdt[CHUNK];
  if (tid < CHUNK * 4)
    reinterpret_cast<float4*>(&sB[0][0])[tid] =
        reinterpret_cast<const float4*>(&Bm[cb * 16])[tid];
  if (tid < CHUNK / 4)
    reinterpret_cast<float4*>(sdt)[tid] =
        reinterpret_cast<const float4*>(&dtr[cb])[tid];
  __syncthreads();

  const float wdt = w_dt[d], bdt = b_dt[d];
  float a[DS2], h[DS2];
#pragma unroll
  for (int q = 0; q < 4; ++q) {
    float4 al = *reinterpret_cast<const float4*>(&A_log[(size_t)d * DS2 + q * 4]);
    a[q * 4 + 0] = -__expf(al.x); a[q * 4 + 1] = -__expf(al.y);
    a[q * 4 + 2] = -__expf(al.z); a[q * 4 + 3] = -__expf(al.w);
  }
#pragma unroll
  for (int n = 0; n < DS2; ++n) h[n] = 0.f;
  float T = 0.f;

#pragma unroll 2
  for (int tt = 0; tt < CHUNK; ++tt) {
    float v = fmaf(sdt[tt], wdt, bdt);
    float dtv = (v > 15.f) ? v : __logf(1.f + __expf(v));
    T += dtv;
    float xv = bf2f(xc[(cb + tt) * DI + d]);
    float s = dtv * xv;
    float bb[DS2];
#pragma unroll
    for (int q = 0; q < 4; ++q)
      *reinterpret_cast<float4*>(&bb[q * 4]) =
          *reinterpret_cast<const float4*>(&sB[tt][q * 4]);
#pragma unroll
    for (int n = 0; n < DS2; ++n)
      h[n] = fmaf(__expf(a[n] * dtv), h[n], s * bb[n]);
  }

  const size_t base = (size_t)(b * NCHUNK + c) * DI + d;
#pragma unroll
  for (int q = 0; q < 4; ++q)
    *reinterpret_cast<float4*>(&hL[base * 16 + q * 4]) =
        *reinterpret_cast<const float4*>(&h[q * 4]);
  Tsum[base] = T;
}

// ---------------- K5b: sequential chunk-combine, in place ------------------
__global__ __launch_bounds__(256) void scan_combine_k(
    float* __restrict__ hLH, const float* __restrict__ Tsum,
    const float* __restrict__ A_log)
{
  int g = blockIdx.x * 256 + threadIdx.x;
  int n = g & 15;
  int d = (g >> 4) % DI;
  int b = g / (DI * DS2);
  const float a = -__expf(A_log[(size_t)d * DS2 + n]);
  float h = 0.f;
  for (int c = 0; c < NCHUNK; ++c) {
    size_t base = (size_t)(b * NCHUNK + c) * DI + d;
    float hl = hLH[base * 16 + n];
    float T = Tsum[base];
    float hprev = h;
    h = fmaf(__expf(a * T), h, hl);
    hLH[base * 16 + n] = hprev;
  }
}

// ---------------- K5c: replay chunk with H_init + fused epilogue -----------
__global__ __launch_bounds__(256) void scan_part3(
    const short* __restrict__ xc,
    const short* __restrict__ xz,    // read z (bf16) at cols 1536..
    short* __restrict__ ybf,
    const float* __restrict__ Bm, const float* __restrict__ Cm,
    const float* __restrict__ dtr,
    const float* __restrict__ w_dt, const float* __restrict__ b_dt,
    const float* __restrict__ A_log, const float* __restrict__ Dp,
    const float* __restrict__ Hinit)
{
  const int blk = blockIdx.x;
  const int c  = blk % NCHUNK;
  const int db = (blk / NCHUNK) % (DI / 256);
  const int b  = blk / (NCHUNK * (DI / 256));
  const int tid = threadIdx.x;
  const int d = db * 256 + tid;
  const size_t cb = (size_t)b * SEQN + c * CHUNK;

  __shared__ float sB[CHUNK][16], sC[CHUNK][16];
  __shared__ float sdt[CHUNK];
  if (tid < CHUNK * 4)
    reinterpret_cast<float4*>(&sB[0][0])[tid] =
        reinterpret_cast<const float4*>(&Bm[cb * 16])[tid];
  else if (tid < CHUNK * 8)
    reinterpret_cast<float4*>(&sC[0][0])[tid - CHUNK * 4] =
        reinterpret_cast<const float4*>(&Cm[cb * 16])[tid - CHUNK * 4];
  if (tid < CHUNK / 4)
    reinterpret_cast<float4*>(sdt)[tid] =
        reinterpret_cast<const float4*>(&dtr[cb])[tid];

  const float wdt = w_dt[d], bdt = b_dt[d];
  const float Dd = Dp[d];
  float a[DS2], h[DS2];
#pragma unroll
  for (int q = 0; q < 4; ++q) {
    float4 al = *reinterpret_cast<const float4*>(&A_log[(size_t)d * DS2 + q * 4]);
    a[q * 4 + 0] = -__expf(al.x); a[q * 4 + 1] = -__expf(al.y);
    a[q * 4 + 2] = -__expf(al.z); a[q * 4 + 3] = -__expf(al.w);
  }
  const size_t base = (size_t)(b * NCHUNK + c) * DI + d;
#pragma unroll
  for (int q = 0; q < 4; ++q)
    *reinterpret_cast<float4*>(&h[q * 4]) =
        *reinterpret_cast<const float4*>(&Hinit[base * 16 + q * 4]);
  __syncthreads();

#pragma unroll 2
  for (int tt = 0; tt < CHUNK; ++tt) {
    float v = fmaf(sdt[tt], wdt, bdt);
    float dtv = (v > 15.f) ? v : __logf(1.f + __expf(v));
    float xv = bf2f(xc[(cb + tt) * DI + d]);
    float s = dtv * xv;
    float bb[DS2], cc[DS2];
#pragma unroll
    for (int q = 0; q < 4; ++q) {
      *reinterpret_cast<float4*>(&bb[q * 4]) =
          *reinterpret_cast<const float4*>(&sB[tt][q * 4]);
      *reinterpret_cast<float4*>(&cc[q * 4]) =
          *reinterpret_cast<const float4*>(&sC[tt][q * 4]);
    }
    float y = 0.f;
#pragma unroll
    for (int n = 0; n < DS2; ++n) {
      h[n] = fmaf(__expf(a[n] * dtv), h[n], s * bb[n]);
      y = fmaf(h[n], cc[n], y);
    }
    const size_t rr = cb + tt;
    float z = bf2f(xz[rr * 3072 + DI + d]);
    float yo = fmaf(xv, Dd, y);
    ybf[rr * DI + d] = (short)f2bf(yo * (z / (1.f + __expf(-z))));
  }
}

// ---------------- launcher -------------------------------------------------
extern "C" void kernel_launch(void* const* d_in, const int* in_sizes, int n_in,
                              void* d_out, int out_size, void* d_ws, size_t ws_size,
                              hipStream_t stream) {
  const float* x      = (const float*)d_in[0];
  const float* norm_w = (const float*)d_in[1];
  const float* w_in   = (const float*)d_in[2];
  const float* conv_w = (const float*)d_in[3];
  const float* conv_b = (const float*)d_in[4];
  const float* w_x    = (const float*)d_in[5];
  const float* w_dt   = (const float*)d_in[6];
  const float* b_dt   = (const float*)d_in[7];
  const float* A_log  = (const float*)d_in[8];
  const float* Dp     = (const float*)d_in[9];
  const float* w_out  = (const float*)d_in[10];
  float* out = (float*)d_out;

  // workspace layout
  float* ws   = (float*)d_ws;
  float* Bm   = ws;                          // 4096 x 16
  float* Cm   = Bm + (size_t)NROWS * 16;
  float* dtr  = Cm + (size_t)NROWS * 16;     // 4096
  float* hL   = dtr + NROWS;                 // B*NCHUNK*DI*16 = 3.1M
  float* Tsum = hL + (size_t)BSZ * NCHUNK * DI * 16;  // 196K
  float* wxT  = Tsum + (size_t)BSZ * NCHUNK * DI;     // 33*1536
  short* xzb  = (short*)(wxT + (size_t)33 * DI);      // 4096 x 3072 bf16
  short* xcb  = xzb + (size_t)NROWS * 2 * DI;         // 4096 x 1536 bf16
  short* xnb  = xcb + (size_t)NROWS * DI;             // 4096 x 768 bf16
  short* winT = xnb + (size_t)NROWS * DM;             // 3072 x 768 bf16
  short* woutT= winT + (size_t)2 * DI * DM;           // 768 x 1536 bf16
  short* ybf  = woutT + (size_t)DM * DI;              // 4096 x 1536 bf16
  // total ~78 MB

  prep_k<<<1024 + 2304 + 1152 + 198, 256, 0, stream>>>(
      x, norm_w, xnb, w_in, winT, w_out, woutT, w_x, wxT);

  // GEMM1: xz(bf16) = xn @ w_in   (M=4096 N=3072 K=768), 128x128, 8 waves
  gemm_bf16<128, 128, true><<<dim3(2 * DI / 128, NROWS / 128), 512, 0, stream>>>(
      xnb, DM, winT, DM, xzb, 2 * DI, DM, nullptr, 0);

  // conv+silu+xssm fused
  conv_xssm_k<<<NROWS / 8, 256, 0, stream>>>(xzb, conv_w, conv_b, wxT,
                                             xcb, Bm, Cm, dtr);

  const int nblk = BSZ * (DI / 256) * NCHUNK;  // 768
  scan_part1<<<nblk, 256, 0, stream>>>(xcb, Bm, dtr, w_dt, b_dt, A_log, hL, Tsum);
  scan_combine_k<<<(BSZ * DI * DS2) / 256, 256, 0, stream>>>(hL, Tsum, A_log);
  scan_part3<<<nblk, 256, 0, stream>>>(xcb, xzb, ybf, Bm, Cm, dtr, w_dt, b_dt,
                                       A_log, Dp, hL);

  // GEMM3: out = x + y @ w_out   (M=4096 N=768 K=1536), 128x64, 8 waves
  gemm_bf16<128, 64, false><<<dim3(DM / 64, NROWS / 128), 512, 0, stream>>>(
      ybf, DI, woutT, DI, out, DM, DI, x, DM);
}